// Round 5
// baseline (474.186 us; speedup 1.0000x reference)
//
#include <hip/hip_runtime.h>
#include <math.h>

#define IN_DIM 128
#define HID 64
#define HEADS 4
#define NEG_SLOPE 0.2f
#define LN_EPS 1e-5f

// ---------- bf16 helpers ----------
__device__ inline unsigned short f2bf(float f) {
    unsigned u = __float_as_uint(f);
    u += 0x7fffu + ((u >> 16) & 1u);     // round-to-nearest-even
    return (unsigned short)(u >> 16);
}
__device__ inline float bf2f(unsigned short s) {
    return __uint_as_float(((unsigned)s) << 16);
}
__device__ inline float leaky(float v) { return v > 0.0f ? v : NEG_SLOPE * v; }

// ---------- zero hist + (block 0) sampled dtype detection ----------
__global__ void k_detect_zero(const unsigned long long* ei, int count, int n,
                              int* flag, int* hist) {
    int i = blockIdx.x * blockDim.x + threadIdx.x;
    if (i < n) hist[i] = 0;
    if (blockIdx.x == 0) {
        __shared__ int s_bad;
        if (threadIdx.x == 0) s_bad = 0;
        __syncthreads();
        int lim = count < 4096 ? count : 4096;
        int bad = 0;
        for (int k = threadIdx.x; k < lim; k += 256)
            if (ei[k] >= (unsigned long long)n) bad = 1;
        if (bad) s_bad = 1;      // benign race
        __syncthreads();
        if (threadIdx.x == 0) *flag = s_bad ? 0 : 1;   // 1 = genuine int64
    }
}

// ---------- remap edge_index to int32 + histogram of dst ----------
__global__ void k_remap_hist(const void* ei, int E, const int* flag,
                             int* edges32, int* hist) {
    int i = blockIdx.x * blockDim.x + threadIdx.x;
    if (i >= 2 * E) return;
    int is64 = *flag;
    int v;
    if (is64) v = (int)((const long long*)ei)[i];
    else      v = ((const int*)ei)[i];
    edges32[i] = v;
    if (i >= E) atomicAdd(&hist[v], 1);    // dst half
}

// ---------- CSR scan ----------
__global__ __launch_bounds__(256) void k_scan1(const int* __restrict__ hist,
                                               int* __restrict__ tmp,
                                               int* __restrict__ partial, int n) {
    __shared__ int s[256];
    int t = threadIdx.x, i = blockIdx.x * 256 + t;
    int v = (i < n) ? hist[i] : 0;
    s[t] = v;
    __syncthreads();
    for (int off = 1; off < 256; off <<= 1) {
        int x = (t >= off) ? s[t - off] : 0;
        __syncthreads();
        s[t] += x;
        __syncthreads();
    }
    tmp[i] = s[t] - v;
    if (t == 255) partial[blockIdx.x] = s[255];
}

// scan of block sums (nb <= 256) + folded att-vector prep
__global__ __launch_bounds__(256) void k_scan2_prep(int* partial, int nb,
                                                    const float* __restrict__ Wg,
                                                    const float* __restrict__ att_s,
                                                    const float* __restrict__ att_d,
                                                    float* __restrict__ w_s,
                                                    float* __restrict__ w_d) {
    __shared__ int s[256];
    int t = threadIdx.x;
    int v = (t < nb) ? partial[t] : 0;
    s[t] = v;
    __syncthreads();
    for (int off = 1; off < 256; off <<= 1) {
        int x = (t >= off) ? s[t - off] : 0;
        __syncthreads();
        s[t] += x;
        __syncthreads();
    }
    if (t < nb) partial[t] = s[t] - v;
    // w_s[h,k] = sum_c Wg[k,h,c]*att_s[h,c]
    int h = t >> 6, k = t & 63;
    float ss = 0.0f, sd = 0.0f;
    for (int c = 0; c < HID; c++) {
        float w = Wg[(size_t)k * (HEADS * HID) + h * HID + c];
        ss += w * att_s[h * HID + c];
        sd += w * att_d[h * HID + c];
    }
    w_s[h * HID + k] = ss;
    w_d[h * HID + k] = sd;
}

__global__ void k_scan3(const int* __restrict__ tmp, const int* __restrict__ partial,
                        const int* __restrict__ hist, int* __restrict__ row_ptr,
                        int* __restrict__ cursor, float* __restrict__ dinv, int n) {
    int i = blockIdx.x * blockDim.x + threadIdx.x;
    if (i >= n) return;
    int v = tmp[i] + partial[i >> 8];
    row_ptr[i] = v;
    cursor[i] = v;
    dinv[i] = rsqrtf((float)(hist[i] + 1));   // +1 self-loop
}

__global__ void k_scatter(const int* __restrict__ src, const int* __restrict__ dst,
                          int* __restrict__ cursor, int* __restrict__ col, int E) {
    int i = blockIdx.x * blockDim.x + threadIdx.x;
    if (i >= E) return;
    int pos = atomicAdd(&cursor[dst[i]], 1);
    col[pos] = src[i];
}

// ---------- xws = bf16( (x @ W_gcn) * dinv[row] ) : [n,128]@[128,64] ----------
__global__ __launch_bounds__(256) void k_xw(const float* __restrict__ x,
                                            const float* __restrict__ W,
                                            const float* __restrict__ dinv,
                                            unsigned short* __restrict__ xws, int n) {
    __shared__ float Wl[IN_DIM * HID];   // 32 KB
    __shared__ float xl[16 * IN_DIM];    // 8 KB
    int t = threadIdx.x;
    for (int i = t; i < IN_DIM * HID; i += 256) Wl[i] = W[i];
    int row0 = blockIdx.x * 16;
    for (int i = t; i < 16 * IN_DIM; i += 256) {
        int r = row0 + (i >> 7);
        xl[i] = (r < n) ? x[(size_t)r * IN_DIM + (i & 127)] : 0.0f;
    }
    __syncthreads();
    int c = t & 63, w = t >> 6;
    for (int j = 0; j < 4; j++) {
        int rl = w * 4 + j;
        float acc = 0.0f;
        for (int k = 0; k < IN_DIM; k++) acc += xl[rl * IN_DIM + k] * Wl[k * HID + c];
        int r = row0 + rl;
        if (r < n) xws[(size_t)r * HID + c] = f2bf(acc * dinv[r]);
    }
}

// ---------- GCN via CSR gather (bf16) + fused bias/relu + attention-logit dots ----------
__global__ __launch_bounds__(256) void k_gcn(const int* __restrict__ col,
                                             const int* __restrict__ row_ptr,
                                             const int* __restrict__ hist,
                                             const float* __restrict__ dinv,
                                             const unsigned short* __restrict__ xws,
                                             const float* __restrict__ b,
                                             const float* __restrict__ w_s,
                                             const float* __restrict__ w_d,
                                             float* __restrict__ h1f,
                                             unsigned short* __restrict__ h1b,
                                             float4* __restrict__ a_s,
                                             float4* __restrict__ a_d, int n) {
    int t = threadIdx.x, c = t & 63;
    int d = blockIdx.x * 4 + (t >> 6);
    if (d >= n) return;
    int start = row_ptr[d], cnt = hist[d];
    float acc = bf2f(xws[(size_t)d * HID + c]);       // self term
    for (int k = 0; k < cnt; k++) {
        int s = col[start + k];
        acc += bf2f(xws[(size_t)s * HID + c]);
    }
    float h1c = fmaxf(acc * dinv[d] + b[c], 0.0f);
    h1f[(size_t)d * HID + c] = h1c;
    h1b[(size_t)d * HID + c] = f2bf(h1c);
    float vs0 = h1c * w_s[c],       vs1 = h1c * w_s[64 + c];
    float vs2 = h1c * w_s[128 + c], vs3 = h1c * w_s[192 + c];
    float vd0 = h1c * w_d[c],       vd1 = h1c * w_d[64 + c];
    float vd2 = h1c * w_d[128 + c], vd3 = h1c * w_d[192 + c];
    for (int o = 32; o > 0; o >>= 1) {
        vs0 += __shfl_xor(vs0, o, 64); vs1 += __shfl_xor(vs1, o, 64);
        vs2 += __shfl_xor(vs2, o, 64); vs3 += __shfl_xor(vs3, o, 64);
        vd0 += __shfl_xor(vd0, o, 64); vd1 += __shfl_xor(vd1, o, 64);
        vd2 += __shfl_xor(vd2, o, 64); vd3 += __shfl_xor(vd3, o, 64);
    }
    if (c == 0) {
        a_s[d] = make_float4(vs0, vs1, vs2, vs3);
        a_d[d] = make_float4(vd0, vd1, vd2, vd3);
    }
}

// ---------- per-(dst,head) softmax normalizer: q = m + ln(sum exp(e-m)) ----------
__global__ __launch_bounds__(256) void k_mq(const int* __restrict__ col,
                                            const int* __restrict__ row_ptr,
                                            const int* __restrict__ hist,
                                            const float* __restrict__ a_s,
                                            const float* __restrict__ a_d,
                                            float* __restrict__ q,
                                            float* __restrict__ aself, int n) {
    int i = blockIdx.x * blockDim.x + threadIdx.x;
    if (i >= n * 4) return;
    int d = i >> 2, h = i & 3;
    float ad = a_d[i];
    float es = leaky(a_s[i] + ad);       // self edge
    float m = es, l = 1.0f;
    int start = row_ptr[d], cnt = hist[d];
    for (int k = 0; k < cnt; k++) {
        int s = col[start + k];
        float e = leaky(a_s[s * 4 + h] + ad);
        float nm = fmaxf(m, e);
        l = l * __expf(m - nm) + __expf(e - nm);
        m = nm;
    }
    float qq = m + __logf(l);
    q[i] = qq;
    aself[i] = __expf(es - qq);
}

// ---------- attention aggregation over h1 (linearity: apply Wg AFTER agg) ----------
// S[d,h,c] = alpha_self_h*h1b[d,c] + sum_s alpha_{s,h}*h1b[s,c]
__global__ __launch_bounds__(256) void k_attn(const int* __restrict__ col,
                                              const int* __restrict__ row_ptr,
                                              const int* __restrict__ hist,
                                              const float4* __restrict__ a_s,
                                              const float4* __restrict__ a_d,
                                              const float4* __restrict__ q,
                                              const float4* __restrict__ aself,
                                              const unsigned short* __restrict__ h1b,
                                              unsigned short* __restrict__ S, int n) {
    int t = threadIdx.x, c = t & 63;
    int d = blockIdx.x * 4 + (t >> 6);
    if (d >= n) return;
    float4 ad = a_d[d], qq = q[d], asf = aself[d];
    float hs = bf2f(h1b[(size_t)d * HID + c]);
    float A0 = asf.x * hs, A1 = asf.y * hs, A2 = asf.z * hs, A3 = asf.w * hs;
    int start = row_ptr[d], cnt = hist[d];
    for (int k = 0; k < cnt; k++) {
        int s = col[start + k];
        float4 as_ = a_s[s];
        float hv = bf2f(h1b[(size_t)s * HID + c]);
        float w0 = __expf(leaky(as_.x + ad.x) - qq.x);
        float w1 = __expf(leaky(as_.y + ad.y) - qq.y);
        float w2 = __expf(leaky(as_.z + ad.z) - qq.z);
        float w3 = __expf(leaky(as_.w + ad.w) - qq.w);
        A0 += w0 * hv; A1 += w1 * hv; A2 += w2 * hv; A3 += w3 * hv;
    }
    size_t base = (size_t)d * 256;
    S[base + c]       = f2bf(A0);
    S[base + 64 + c]  = f2bf(A1);
    S[base + 128 + c] = f2bf(A2);
    S[base + 192 + c] = f2bf(A3);
}

// ---------- post: agg = [S]@[0.25*Wg stacked] ; hp = h1@Wp ; residual + LN ----------
// X = [S(256) | h1b(64)] per row (bf16 pairs), W = [0.25*Wg'(256) | Wp(64)] per col.
#define PR 32
__global__ __launch_bounds__(256) void k_post(const unsigned short* __restrict__ S,
                                              const unsigned short* __restrict__ h1b,
                                              const float* __restrict__ h1f,
                                              const float* __restrict__ Wg,
                                              const float* __restrict__ Wp,
                                              const float* __restrict__ bp,
                                              const float* __restrict__ bg,
                                              const float* __restrict__ gamma,
                                              const float* __restrict__ beta,
                                              float* __restrict__ out, int n) {
    __shared__ unsigned X2[PR][162];   // 160 used + 2 pad (bank decorrelation)
    __shared__ unsigned W2[64][162];
    int t = threadIdx.x;
    // stage W2: pair jj packs j=2jj (lo) and j=2jj+1 (hi)
    for (int i = t; i < 64 * 160; i += 256) {
        int c = i & 63, jj = i >> 6;
        int j0 = jj * 2;
        float f0, f1;
        if (j0 < 256) {
            int h0 = j0 >> 6, k0 = j0 & 63;
            f0 = 0.25f * Wg[(size_t)k0 * 256 + h0 * 64 + c];
            int j1 = j0 + 1, h1_ = j1 >> 6, k1 = j1 & 63;
            f1 = 0.25f * Wg[(size_t)k1 * 256 + h1_ * 64 + c];
        } else {
            f0 = Wp[(size_t)(j0 - 256) * 64 + c];
            f1 = Wp[(size_t)(j0 - 255) * 64 + c];
        }
        W2[c][jj] = ((unsigned)f2bf(f1) << 16) | (unsigned)f2bf(f0);
    }
    int r0 = blockIdx.x * PR;
    const unsigned* S32 = (const unsigned*)S;
    const unsigned* H32 = (const unsigned*)h1b;
    for (int i = t; i < PR * 160; i += 256) {
        int jj = i % 160, r = i / 160;
        int rr = r0 + r;
        unsigned v = 0;
        if (rr < n) v = (jj < 128) ? S32[(size_t)rr * 128 + jj]
                                   : H32[(size_t)rr * 32 + (jj - 128)];
        X2[r][jj] = v;
    }
    __syncthreads();
    int c = t & 63, w = t >> 6;
    for (int rl = w * 8; rl < w * 8 + 8; rl++) {
        int r = r0 + rl;
        if (r >= n) continue;             // wave-uniform: whole wave skips together
        float agg = 0.0f, hp = 0.0f;
        for (int jj = 0; jj < 128; jj++) {
            unsigned u = X2[rl][jj], v = W2[c][jj];
            agg += __uint_as_float(u << 16) * __uint_as_float(v << 16);
            agg += __uint_as_float(u & 0xffff0000u) * __uint_as_float(v & 0xffff0000u);
        }
        for (int jj = 128; jj < 160; jj++) {
            unsigned u = X2[rl][jj], v = W2[c][jj];
            hp += __uint_as_float(u << 16) * __uint_as_float(v << 16);
            hp += __uint_as_float(u & 0xffff0000u) * __uint_as_float(v & 0xffff0000u);
        }
        float h1c = h1f[(size_t)r * HID + c];
        float h2 = fmaxf(agg + bg[c], 0.0f);   // 0.25 head-mean folded into W
        float h = h1c + h2 + hp + bp[c];
        float s1 = h, s2 = h * h;
        for (int o = 32; o > 0; o >>= 1) {
            s1 += __shfl_xor(s1, o, 64);
            s2 += __shfl_xor(s2, o, 64);
        }
        float mu = s1 * (1.0f / 64.0f);
        float var = s2 * (1.0f / 64.0f) - mu * mu;
        out[(size_t)r * HID + c] = (h - mu) * rsqrtf(var + LN_EPS) * gamma[c] + beta[c];
    }
}

extern "C" void kernel_launch(void* const* d_in, const int* in_sizes, int n_in,
                              void* d_out, int out_size, void* d_ws, size_t ws_size,
                              hipStream_t stream) {
    int n = in_sizes[0] / IN_DIM;
    int E = in_sizes[1] / 2;

    const float* x     = (const float*)d_in[0];
    const void*  ei    = d_in[1];
    const float* W_gcn = (const float*)d_in[2];
    const float* b_gcn = (const float*)d_in[3];
    const float* W_gat = (const float*)d_in[4];
    const float* att_s = (const float*)d_in[5];
    const float* att_d = (const float*)d_in[6];
    const float* b_gat = (const float*)d_in[7];
    const float* W_p   = (const float*)d_in[8];
    const float* b_p   = (const float*)d_in[9];
    const float* gamma = (const float*)d_in[10];
    const float* beta  = (const float*)d_in[11];

    int n_pad = ((n + 255) / 256) * 256;
    int nscan = n_pad / 256;                 // must be <= 256

    float* ws = (float*)d_ws;
    size_t off = 0;
    int*   flag    = (int*)(ws + off);  off += 4;
    int*   edges   = (int*)(ws + off);  off += (size_t)2 * E;
    int*   hist    = (int*)(ws + off);  off += n;
    int*   row_ptr = (int*)(ws + off);  off += n;
    int*   cursor  = (int*)(ws + off);  off += n;
    int*   tmp     = (int*)(ws + off);  off += n_pad;
    int*   partial = (int*)(ws + off);  off += 256;
    int*   colv    = (int*)(ws + off);  off += E;
    float* dinv    = ws + off;          off += n;
    float* w_s     = ws + off;          off += HEADS * HID;
    float* w_d     = ws + off;          off += HEADS * HID;
    off = (off + 3) & ~(size_t)3;
    unsigned short* xws = (unsigned short*)(ws + off); off += (size_t)n * HID / 2;
    float* h1f     = ws + off;          off += (size_t)n * HID;
    off = (off + 3) & ~(size_t)3;
    unsigned short* h1b = (unsigned short*)(ws + off); off += (size_t)n * HID / 2;
    off = (off + 3) & ~(size_t)3;
    float4* a_sv   = (float4*)(ws + off); off += (size_t)n * 4;
    float4* a_dv   = (float4*)(ws + off); off += (size_t)n * 4;
    float4* qv     = (float4*)(ws + off); off += (size_t)n * 4;
    float4* aself  = (float4*)(ws + off); off += (size_t)n * 4;
    unsigned short* S = (unsigned short*)(ws + off); off += (size_t)n * HEADS * HID / 2;

    const int* src = edges;
    const int* dst = edges + E;

    // detect dtype (block 0) + zero hist
    k_detect_zero<<<(n + 255) / 256, 256, 0, stream>>>(
        (const unsigned long long*)ei, E, n, flag, hist);
    // remap to int32 + dst histogram
    k_remap_hist<<<(2 * E + 255) / 256, 256, 0, stream>>>(ei, E, flag, edges, hist);

    // CSR scan + scatter (+ folded att prep)
    k_scan1<<<nscan, 256, 0, stream>>>(hist, tmp, partial, n);
    k_scan2_prep<<<1, 256, 0, stream>>>(partial, nscan, W_gat, att_s, att_d, w_s, w_d);
    k_scan3<<<nscan, 256, 0, stream>>>(tmp, partial, hist, row_ptr, cursor, dinv, n);
    k_scatter<<<(E + 255) / 256, 256, 0, stream>>>(src, dst, cursor, colv, E);

    // dense GCN projection (bf16, pre-scaled by dinv)
    k_xw<<<(n + 15) / 16, 256, 0, stream>>>(x, W_gcn, dinv, xws, n);

    // GCN gather + logit dots
    k_gcn<<<(n + 3) / 4, 256, 0, stream>>>(colv, row_ptr, hist, dinv, xws, b_gcn,
                                           w_s, w_d, h1f, h1b, a_sv, a_dv, n);

    // softmax normalizers
    k_mq<<<(n * 4 + 255) / 256, 256, 0, stream>>>(colv, row_ptr, hist,
                                                  (const float*)a_sv, (const float*)a_dv,
                                                  (float*)qv, (float*)aself, n);

    // attention aggregation of h1 (no z)
    k_attn<<<(n + 3) / 4, 256, 0, stream>>>(colv, row_ptr, hist, a_sv, a_dv, qv,
                                            aself, h1b, S, n);

    // post GEMM + patch + residual + LN
    k_post<<<(n + PR - 1) / PR, 256, 0, stream>>>(S, h1b, h1f, W_gat, W_p, b_p, b_gat,
                                                  gamma, beta, (float*)d_out, n);
}

// Round 6
// 338.192 us; speedup vs baseline: 1.4021x; 1.4021x over previous
//
#include <hip/hip_runtime.h>
#include <math.h>

#define IN_DIM 128
#define HID 64
#define HEADS 4
#define NEG_SLOPE 0.2f
#define LN_EPS 1e-5f
#define XK 320              // stacked K dim: 256 (S) + 64 (h1)

typedef short bf16x8 __attribute__((ext_vector_type(8)));
typedef float f32x4  __attribute__((ext_vector_type(4)));

// ---------- bf16 helpers ----------
__device__ inline unsigned short f2bf(float f) {
    unsigned u = __float_as_uint(f);
    u += 0x7fffu + ((u >> 16) & 1u);     // round-to-nearest-even
    return (unsigned short)(u >> 16);
}
__device__ inline float bf2f(unsigned short s) {
    return __uint_as_float(((unsigned)s) << 16);
}
__device__ inline float leaky(float v) { return v > 0.0f ? v : NEG_SLOPE * v; }

// ---------- zero hist + (block 0) sampled dtype detection ----------
__global__ void k_detect_zero(const unsigned long long* ei, int count, int n,
                              int* flag, int* hist) {
    int i = blockIdx.x * blockDim.x + threadIdx.x;
    if (i < n) hist[i] = 0;
    if (blockIdx.x == 0) {
        __shared__ int s_bad;
        if (threadIdx.x == 0) s_bad = 0;
        __syncthreads();
        int lim = count < 4096 ? count : 4096;
        int bad = 0;
        for (int k = threadIdx.x; k < lim; k += 256)
            if (ei[k] >= (unsigned long long)n) bad = 1;
        if (bad) s_bad = 1;      // benign race
        __syncthreads();
        if (threadIdx.x == 0) *flag = s_bad ? 0 : 1;   // 1 = genuine int64
    }
}

// ---------- remap edge_index to int32 + histogram of dst ----------
__global__ void k_remap_hist(const void* ei, int E, const int* flag,
                             int* edges32, int* hist) {
    int i = blockIdx.x * blockDim.x + threadIdx.x;
    if (i >= 2 * E) return;
    int is64 = *flag;
    int v;
    if (is64) v = (int)((const long long*)ei)[i];
    else      v = ((const int*)ei)[i];
    edges32[i] = v;
    if (i >= E) atomicAdd(&hist[v], 1);    // dst half
}

// ---------- CSR scan ----------
__global__ __launch_bounds__(256) void k_scan1(const int* __restrict__ hist,
                                               int* __restrict__ tmp,
                                               int* __restrict__ partial, int n) {
    __shared__ int s[256];
    int t = threadIdx.x, i = blockIdx.x * 256 + t;
    int v = (i < n) ? hist[i] : 0;
    s[t] = v;
    __syncthreads();
    for (int off = 1; off < 256; off <<= 1) {
        int x = (t >= off) ? s[t - off] : 0;
        __syncthreads();
        s[t] += x;
        __syncthreads();
    }
    tmp[i] = s[t] - v;
    if (t == 255) partial[blockIdx.x] = s[255];
}

// scan of block sums (nb <= 256) + folded att-vector prep
__global__ __launch_bounds__(256) void k_scan2_prep(int* partial, int nb,
                                                    const float* __restrict__ Wg,
                                                    const float* __restrict__ att_s,
                                                    const float* __restrict__ att_d,
                                                    float* __restrict__ w_s,
                                                    float* __restrict__ w_d) {
    __shared__ int s[256];
    int t = threadIdx.x;
    int v = (t < nb) ? partial[t] : 0;
    s[t] = v;
    __syncthreads();
    for (int off = 1; off < 256; off <<= 1) {
        int x = (t >= off) ? s[t - off] : 0;
        __syncthreads();
        s[t] += x;
        __syncthreads();
    }
    if (t < nb) partial[t] = s[t] - v;
    int h = t >> 6, k = t & 63;
    float ss = 0.0f, sd = 0.0f;
    for (int c = 0; c < HID; c++) {
        float w = Wg[(size_t)k * (HEADS * HID) + h * HID + c];
        ss += w * att_s[h * HID + c];
        sd += w * att_d[h * HID + c];
    }
    w_s[h * HID + k] = ss;
    w_d[h * HID + k] = sd;
}

__global__ void k_scan3(const int* __restrict__ tmp, const int* __restrict__ partial,
                        const int* __restrict__ hist, int* __restrict__ row_ptr,
                        int* __restrict__ cursor, float* __restrict__ dinv, int n) {
    int i = blockIdx.x * blockDim.x + threadIdx.x;
    if (i >= n) return;
    int v = tmp[i] + partial[i >> 8];
    row_ptr[i] = v;
    cursor[i] = v;
    dinv[i] = rsqrtf((float)(hist[i] + 1));   // +1 self-loop
}

__global__ void k_scatter(const int* __restrict__ src, const int* __restrict__ dst,
                          int* __restrict__ cursor, int* __restrict__ col, int E) {
    int i = blockIdx.x * blockDim.x + threadIdx.x;
    if (i >= E) return;
    int pos = atomicAdd(&cursor[dst[i]], 1);
    col[pos] = src[i];
}

// ---------- xws = bf16( (x @ W_gcn) * dinv[row] ) ----------
__global__ __launch_bounds__(256) void k_xw(const float* __restrict__ x,
                                            const float* __restrict__ W,
                                            const float* __restrict__ dinv,
                                            unsigned short* __restrict__ xws, int n) {
    __shared__ float Wl[IN_DIM * HID];   // 32 KB
    __shared__ float xl[16 * IN_DIM];    // 8 KB
    int t = threadIdx.x;
    for (int i = t; i < IN_DIM * HID; i += 256) Wl[i] = W[i];
    int row0 = blockIdx.x * 16;
    for (int i = t; i < 16 * IN_DIM; i += 256) {
        int r = row0 + (i >> 7);
        xl[i] = (r < n) ? x[(size_t)r * IN_DIM + (i & 127)] : 0.0f;
    }
    __syncthreads();
    int c = t & 63, w = t >> 6;
    for (int j = 0; j < 4; j++) {
        int rl = w * 4 + j;
        float acc = 0.0f;
        for (int k = 0; k < IN_DIM; k++) acc += xl[rl * IN_DIM + k] * Wl[k * HID + c];
        int r = row0 + rl;
        if (r < n) xws[(size_t)r * HID + c] = f2bf(acc * dinv[r]);
    }
}

// ---------- GCN gather + bias/relu + logit dots; h1 -> f32, compact bf16, X cols 256..319 ----------
__global__ __launch_bounds__(256) void k_gcn(const int* __restrict__ col,
                                             const int* __restrict__ row_ptr,
                                             const int* __restrict__ hist,
                                             const float* __restrict__ dinv,
                                             const unsigned short* __restrict__ xws,
                                             const float* __restrict__ b,
                                             const float* __restrict__ w_s,
                                             const float* __restrict__ w_d,
                                             float* __restrict__ h1f,
                                             unsigned short* __restrict__ h1b,
                                             unsigned short* __restrict__ X,
                                             float4* __restrict__ a_s,
                                             float4* __restrict__ a_d, int n) {
    int t = threadIdx.x, c = t & 63;
    int d = blockIdx.x * 4 + (t >> 6);
    if (d >= n) return;
    int start = row_ptr[d], cnt = hist[d];
    float acc = bf2f(xws[(size_t)d * HID + c]);       // self term
    for (int k = 0; k < cnt; k++) {
        int s = col[start + k];
        acc += bf2f(xws[(size_t)s * HID + c]);
    }
    float h1c = fmaxf(acc * dinv[d] + b[c], 0.0f);
    h1f[(size_t)d * HID + c] = h1c;
    unsigned short hb = f2bf(h1c);
    h1b[(size_t)d * HID + c] = hb;
    X[(size_t)d * XK + 256 + c] = hb;
    float vs0 = h1c * w_s[c],       vs1 = h1c * w_s[64 + c];
    float vs2 = h1c * w_s[128 + c], vs3 = h1c * w_s[192 + c];
    float vd0 = h1c * w_d[c],       vd1 = h1c * w_d[64 + c];
    float vd2 = h1c * w_d[128 + c], vd3 = h1c * w_d[192 + c];
    for (int o = 32; o > 0; o >>= 1) {
        vs0 += __shfl_xor(vs0, o, 64); vs1 += __shfl_xor(vs1, o, 64);
        vs2 += __shfl_xor(vs2, o, 64); vs3 += __shfl_xor(vs3, o, 64);
        vd0 += __shfl_xor(vd0, o, 64); vd1 += __shfl_xor(vd1, o, 64);
        vd2 += __shfl_xor(vd2, o, 64); vd3 += __shfl_xor(vd3, o, 64);
    }
    if (c == 0) {
        a_s[d] = make_float4(vs0, vs1, vs2, vs3);
        a_d[d] = make_float4(vd0, vd1, vd2, vd3);
    }
}

// ---------- per-(dst,head) softmax normalizer ----------
__global__ __launch_bounds__(256) void k_mq(const int* __restrict__ col,
                                            const int* __restrict__ row_ptr,
                                            const int* __restrict__ hist,
                                            const float* __restrict__ a_s,
                                            const float* __restrict__ a_d,
                                            float* __restrict__ q,
                                            float* __restrict__ aself, int n) {
    int i = blockIdx.x * blockDim.x + threadIdx.x;
    if (i >= n * 4) return;
    int d = i >> 2, h = i & 3;
    float ad = a_d[i];
    float es = leaky(a_s[i] + ad);       // self edge
    float m = es, l = 1.0f;
    int start = row_ptr[d], cnt = hist[d];
    for (int k = 0; k < cnt; k++) {
        int s = col[start + k];
        float e = leaky(a_s[s * 4 + h] + ad);
        float nm = fmaxf(m, e);
        l = l * __expf(m - nm) + __expf(e - nm);
        m = nm;
    }
    float qq = m + __logf(l);
    q[i] = qq;
    aself[i] = __expf(es - qq);
}

// ---------- attention aggregation of h1 (linearity); writes X cols 0..255 ----------
__global__ __launch_bounds__(256) void k_attn(const int* __restrict__ col,
                                              const int* __restrict__ row_ptr,
                                              const int* __restrict__ hist,
                                              const float4* __restrict__ a_s,
                                              const float4* __restrict__ a_d,
                                              const float4* __restrict__ q,
                                              const float4* __restrict__ aself,
                                              const unsigned short* __restrict__ h1b,
                                              unsigned short* __restrict__ X, int n) {
    int t = threadIdx.x, c = t & 63;
    int d = blockIdx.x * 4 + (t >> 6);
    if (d >= n) return;
    float4 ad = a_d[d], qq = q[d], asf = aself[d];
    float hs = bf2f(h1b[(size_t)d * HID + c]);
    float A0 = asf.x * hs, A1 = asf.y * hs, A2 = asf.z * hs, A3 = asf.w * hs;
    int start = row_ptr[d], cnt = hist[d];
    for (int k = 0; k < cnt; k++) {
        int s = col[start + k];
        float4 as_ = a_s[s];
        float hv = bf2f(h1b[(size_t)s * HID + c]);
        float w0 = __expf(leaky(as_.x + ad.x) - qq.x);
        float w1 = __expf(leaky(as_.y + ad.y) - qq.y);
        float w2 = __expf(leaky(as_.z + ad.z) - qq.z);
        float w3 = __expf(leaky(as_.w + ad.w) - qq.w);
        A0 += w0 * hv; A1 += w1 * hv; A2 += w2 * hv; A3 += w3 * hv;
    }
    size_t base = (size_t)d * XK;
    X[base + c]       = f2bf(A0);
    X[base + 64 + c]  = f2bf(A1);
    X[base + 128 + c] = f2bf(A2);
    X[base + 192 + c] = f2bf(A3);
}

// ---------- post: MFMA GEMM X[n,320] @ [0.25*Wg' ; Wp] -> agg|hp, + relu/residual/LN ----------
// W'[j][c]: j<256 -> 0.25*Wg[(j&63)][ (j>>6)*64 + c ]; j>=256 -> Wp[j-256][c].
// LDS Wt[kg][c][jin] (kg=j>>3, jin=j&7): b-frag ds_read_b128 contiguous per quad.
__global__ __launch_bounds__(256) void k_post(const unsigned short* __restrict__ X,
                                              const float* __restrict__ h1f,
                                              const float* __restrict__ Wg,
                                              const float* __restrict__ Wp,
                                              const float* __restrict__ bp,
                                              const float* __restrict__ bg,
                                              const float* __restrict__ gamma,
                                              const float* __restrict__ beta,
                                              float* __restrict__ out, int n) {
    __shared__ unsigned short Wt[40 * 64 * 8];   // 40 KB
    int t = threadIdx.x;
    // stage W' -> LDS (idx = k*64 + c, coalesced on c)
    for (int idx = t; idx < XK * 64; idx += 256) {
        int c = idx & 63, k = idx >> 6;
        float f;
        if (k < 256) f = 0.25f * Wg[(size_t)(k & 63) * 256 + (k >> 6) * 64 + c];
        else         f = Wp[(size_t)(k - 256) * 64 + c];
        Wt[(((k >> 3) * 64) + c) * 8 + (k & 7)] = f2bf(f);
    }
    __syncthreads();

    int lane = t & 63;
    int li = lane & 15, quad = lane >> 4;
    int w = t >> 6;
    int r0 = blockIdx.x * 64 + w * 16;           // 16 rows per wave

    f32x4 acc_a[4], acc_h[4];
#pragma unroll
    for (int i = 0; i < 4; i++) {
        acc_a[i] = (f32x4){0.f, 0.f, 0.f, 0.f};
        acc_h[i] = (f32x4){0.f, 0.f, 0.f, 0.f};
    }
    const unsigned short* xrow = X + (size_t)(r0 + li) * XK + quad * 8;
#pragma unroll
    for (int ks = 0; ks < 10; ks++) {
        bf16x8 a = *(const bf16x8*)(xrow + ks * 32);
        int kg = ks * 4 + quad;
#pragma unroll
        for (int tt = 0; tt < 4; tt++) {
            bf16x8 bfr = *(const bf16x8*)(&Wt[((kg * 64) + tt * 16 + li) * 8]);
            if (ks < 8)
                acc_a[tt] = __builtin_amdgcn_mfma_f32_16x16x32_bf16(a, bfr, acc_a[tt], 0, 0, 0);
            else
                acc_h[tt] = __builtin_amdgcn_mfma_f32_16x16x32_bf16(a, bfr, acc_h[tt], 0, 0, 0);
        }
    }
    // epilogue: per lane, rows r0+quad*4+reg, cols tt*16+li
    float bgv[4], bpv[4], gv[4], btv[4];
#pragma unroll
    for (int tt = 0; tt < 4; tt++) {
        int c = tt * 16 + li;
        bgv[tt] = bg[c]; bpv[tt] = bp[c]; gv[tt] = gamma[c]; btv[tt] = beta[c];
    }
#pragma unroll
    for (int reg = 0; reg < 4; reg++) {
        int r = r0 + quad * 4 + reg;
        bool ok = (r < n);
        float hv[4];
        float s1 = 0.0f, s2 = 0.0f;
#pragma unroll
        for (int tt = 0; tt < 4; tt++) {
            int c = tt * 16 + li;
            float h1c = ok ? h1f[(size_t)r * HID + c] : 0.0f;
            float h2 = fmaxf(acc_a[tt][reg] + bgv[tt], 0.0f);
            float h = h1c + h2 + acc_h[tt][reg] + bpv[tt];
            hv[tt] = h;
            s1 += h; s2 += h * h;
        }
        // reduce across the 16-lane quad group (cols of this row)
        for (int o = 8; o > 0; o >>= 1) {
            s1 += __shfl_xor(s1, o, 64);
            s2 += __shfl_xor(s2, o, 64);
        }
        float mu = s1 * (1.0f / 64.0f);
        float var = s2 * (1.0f / 64.0f) - mu * mu;
        float rs = rsqrtf(var + LN_EPS);
        if (ok) {
#pragma unroll
            for (int tt = 0; tt < 4; tt++) {
                int c = tt * 16 + li;
                out[(size_t)r * HID + c] = (hv[tt] - mu) * rs * gv[tt] + btv[tt];
            }
        }
    }
}

extern "C" void kernel_launch(void* const* d_in, const int* in_sizes, int n_in,
                              void* d_out, int out_size, void* d_ws, size_t ws_size,
                              hipStream_t stream) {
    int n = in_sizes[0] / IN_DIM;
    int E = in_sizes[1] / 2;

    const float* x     = (const float*)d_in[0];
    const void*  ei    = d_in[1];
    const float* W_gcn = (const float*)d_in[2];
    const float* b_gcn = (const float*)d_in[3];
    const float* W_gat = (const float*)d_in[4];
    const float* att_s = (const float*)d_in[5];
    const float* att_d = (const float*)d_in[6];
    const float* b_gat = (const float*)d_in[7];
    const float* W_p   = (const float*)d_in[8];
    const float* b_p   = (const float*)d_in[9];
    const float* gamma = (const float*)d_in[10];
    const float* beta  = (const float*)d_in[11];

    int n_pad = ((n + 255) / 256) * 256;
    int nscan = n_pad / 256;                 // must be <= 256
    int n64   = ((n + 63) / 64) * 64;        // row padding for MFMA tiles

    float* ws = (float*)d_ws;
    size_t off = 0;
    int*   flag    = (int*)(ws + off);  off += 4;
    int*   edges   = (int*)(ws + off);  off += (size_t)2 * E;
    int*   hist    = (int*)(ws + off);  off += n;
    int*   row_ptr = (int*)(ws + off);  off += n;
    int*   cursor  = (int*)(ws + off);  off += n;
    int*   tmp     = (int*)(ws + off);  off += n_pad;
    int*   partial = (int*)(ws + off);  off += 256;
    int*   colv    = (int*)(ws + off);  off += E;
    float* dinv    = ws + off;          off += n;
    float* w_s     = ws + off;          off += HEADS * HID;
    float* w_d     = ws + off;          off += HEADS * HID;
    off = (off + 3) & ~(size_t)3;
    unsigned short* xws = (unsigned short*)(ws + off); off += (size_t)n * HID / 2;
    float* h1f     = ws + off;          off += (size_t)n * HID;
    off = (off + 3) & ~(size_t)3;
    unsigned short* h1b = (unsigned short*)(ws + off); off += (size_t)n * HID / 2;
    off = (off + 3) & ~(size_t)3;
    float4* a_sv   = (float4*)(ws + off); off += (size_t)n * 4;
    float4* a_dv   = (float4*)(ws + off); off += (size_t)n * 4;
    float4* qv     = (float4*)(ws + off); off += (size_t)n * 4;
    float4* aself  = (float4*)(ws + off); off += (size_t)n * 4;
    off = (off + 3) & ~(size_t)3;
    unsigned short* X = (unsigned short*)(ws + off); off += (size_t)n64 * XK / 2;

    const int* src = edges;
    const int* dst = edges + E;

    // detect dtype (block 0) + zero hist
    k_detect_zero<<<(n + 255) / 256, 256, 0, stream>>>(
        (const unsigned long long*)ei, E, n, flag, hist);
    // remap to int32 + dst histogram
    k_remap_hist<<<(2 * E + 255) / 256, 256, 0, stream>>>(ei, E, flag, edges, hist);

    // CSR scan + scatter (+ folded att prep)
    k_scan1<<<nscan, 256, 0, stream>>>(hist, tmp, partial, n);
    k_scan2_prep<<<1, 256, 0, stream>>>(partial, nscan, W_gat, att_s, att_d, w_s, w_d);
    k_scan3<<<nscan, 256, 0, stream>>>(tmp, partial, hist, row_ptr, cursor, dinv, n);
    k_scatter<<<(E + 255) / 256, 256, 0, stream>>>(src, dst, cursor, colv, E);

    // dense GCN projection (bf16, pre-scaled by dinv)
    k_xw<<<(n + 15) / 16, 256, 0, stream>>>(x, W_gcn, dinv, xws, n);

    // GCN gather + logit dots
    k_gcn<<<(n + 3) / 4, 256, 0, stream>>>(colv, row_ptr, hist, dinv, xws, b_gcn,
                                           w_s, w_d, h1f, h1b, X, a_sv, a_dv, n);

    // softmax normalizers
    k_mq<<<(n * 4 + 255) / 256, 256, 0, stream>>>(colv, row_ptr, hist,
                                                  (const float*)a_sv, (const float*)a_dv,
                                                  (float*)qv, (float*)aself, n);

    // attention aggregation of h1 -> X cols 0..255
    k_attn<<<(n + 3) / 4, 256, 0, stream>>>(colv, row_ptr, hist, a_sv, a_dv, qv,
                                            aself, h1b, X, n);

    // MFMA post GEMM + relu/residual/LN
    k_post<<<(n + 63) / 64, 256, 0, stream>>>(X, h1f, W_gat, W_p, b_p, b_gat,
                                              gamma, beta, (float*)d_out, n);
}

// Round 7
// 302.120 us; speedup vs baseline: 1.5695x; 1.1194x over previous
//
#include <hip/hip_runtime.h>
#include <math.h>

#define IN_DIM 128
#define HID 64
#define HEADS 4
#define NEG_SLOPE 0.2f
#define LN_EPS 1e-5f
#define XK 320              // stacked K dim: 256 (S) + 64 (h1)

typedef short bf16x8 __attribute__((ext_vector_type(8)));
typedef float f32x4  __attribute__((ext_vector_type(4)));

// ---------- bf16 helpers ----------
__device__ inline unsigned short f2bf(float f) {
    unsigned u = __float_as_uint(f);
    u += 0x7fffu + ((u >> 16) & 1u);     // round-to-nearest-even
    return (unsigned short)(u >> 16);
}
__device__ inline float bf2f(unsigned short s) {
    return __uint_as_float(((unsigned)s) << 16);
}
__device__ inline float leaky(float v) { return v > 0.0f ? v : NEG_SLOPE * v; }

// ---------- zero hist + (block 0) sampled dtype detection ----------
__global__ void k_detect_zero(const unsigned long long* ei, int count, int n,
                              int* flag, int* hist) {
    int i = blockIdx.x * blockDim.x + threadIdx.x;
    if (i < n) hist[i] = 0;
    if (blockIdx.x == 0) {
        __shared__ int s_bad;
        if (threadIdx.x == 0) s_bad = 0;
        __syncthreads();
        int lim = count < 4096 ? count : 4096;
        int bad = 0;
        for (int k = threadIdx.x; k < lim; k += 256)
            if (ei[k] >= (unsigned long long)n) bad = 1;
        if (bad) s_bad = 1;      // benign race
        __syncthreads();
        if (threadIdx.x == 0) *flag = s_bad ? 0 : 1;   // 1 = genuine int64
    }
}

// ---------- remap edge_index to int32 + histogram of dst ----------
__global__ void k_remap_hist(const void* ei, int E, const int* flag,
                             int* edges32, int* hist) {
    int i = blockIdx.x * blockDim.x + threadIdx.x;
    if (i >= 2 * E) return;
    int is64 = *flag;
    int v;
    if (is64) v = (int)((const long long*)ei)[i];
    else      v = ((const int*)ei)[i];
    edges32[i] = v;
    if (i >= E) atomicAdd(&hist[v], 1);    // dst half
}

// ---------- CSR scan ----------
__global__ __launch_bounds__(256) void k_scan1(const int* __restrict__ hist,
                                               int* __restrict__ tmp,
                                               int* __restrict__ partial, int n) {
    __shared__ int s[256];
    int t = threadIdx.x, i = blockIdx.x * 256 + t;
    int v = (i < n) ? hist[i] : 0;
    s[t] = v;
    __syncthreads();
    for (int off = 1; off < 256; off <<= 1) {
        int x = (t >= off) ? s[t - off] : 0;
        __syncthreads();
        s[t] += x;
        __syncthreads();
    }
    tmp[i] = s[t] - v;
    if (t == 255) partial[blockIdx.x] = s[255];
}

// scan of block sums (nb <= 256) + folded att-vector prep
__global__ __launch_bounds__(256) void k_scan2_prep(int* partial, int nb,
                                                    const float* __restrict__ Wg,
                                                    const float* __restrict__ att_s,
                                                    const float* __restrict__ att_d,
                                                    float* __restrict__ w_s,
                                                    float* __restrict__ w_d) {
    __shared__ int s[256];
    int t = threadIdx.x;
    int v = (t < nb) ? partial[t] : 0;
    s[t] = v;
    __syncthreads();
    for (int off = 1; off < 256; off <<= 1) {
        int x = (t >= off) ? s[t - off] : 0;
        __syncthreads();
        s[t] += x;
        __syncthreads();
    }
    if (t < nb) partial[t] = s[t] - v;
    int h = t >> 6, k = t & 63;
    float ss = 0.0f, sd = 0.0f;
    for (int c = 0; c < HID; c++) {
        float w = Wg[(size_t)k * (HEADS * HID) + h * HID + c];
        ss += w * att_s[h * HID + c];
        sd += w * att_d[h * HID + c];
    }
    w_s[h * HID + k] = ss;
    w_d[h * HID + k] = sd;
}

__global__ void k_scan3(const int* __restrict__ tmp, const int* __restrict__ partial,
                        const int* __restrict__ hist, int* __restrict__ row_ptr,
                        int* __restrict__ cursor, float* __restrict__ dinv, int n) {
    int i = blockIdx.x * blockDim.x + threadIdx.x;
    if (i >= n) return;
    int v = tmp[i] + partial[i >> 8];
    row_ptr[i] = v;
    cursor[i] = v;
    dinv[i] = rsqrtf((float)(hist[i] + 1));   // +1 self-loop
}

__global__ void k_scatter(const int* __restrict__ src, const int* __restrict__ dst,
                          int* __restrict__ cursor, int* __restrict__ col, int E) {
    int i = blockIdx.x * blockDim.x + threadIdx.x;
    if (i >= E) return;
    int pos = atomicAdd(&cursor[dst[i]], 1);
    col[pos] = src[i];
}

// ---------- xws = bf16( (x @ W_gcn) * dinv[row] ) ----------
__global__ __launch_bounds__(256) void k_xw(const float* __restrict__ x,
                                            const float* __restrict__ W,
                                            const float* __restrict__ dinv,
                                            unsigned short* __restrict__ xws, int n) {
    __shared__ float Wl[IN_DIM * HID];   // 32 KB
    __shared__ float xl[16 * IN_DIM];    // 8 KB
    int t = threadIdx.x;
    for (int i = t; i < IN_DIM * HID; i += 256) Wl[i] = W[i];
    int row0 = blockIdx.x * 16;
    for (int i = t; i < 16 * IN_DIM; i += 256) {
        int r = row0 + (i >> 7);
        xl[i] = (r < n) ? x[(size_t)r * IN_DIM + (i & 127)] : 0.0f;
    }
    __syncthreads();
    int c = t & 63, w = t >> 6;
    for (int j = 0; j < 4; j++) {
        int rl = w * 4 + j;
        float acc = 0.0f;
        for (int k = 0; k < IN_DIM; k++) acc += xl[rl * IN_DIM + k] * Wl[k * HID + c];
        int r = row0 + rl;
        if (r < n) xws[(size_t)r * HID + c] = f2bf(acc * dinv[r]);
    }
}

// ---------- GCN gather + bias/relu + logit dots; h1 -> f32, compact bf16, X cols 256..319 ----------
__global__ __launch_bounds__(256) void k_gcn(const int* __restrict__ col,
                                             const int* __restrict__ row_ptr,
                                             const int* __restrict__ hist,
                                             const float* __restrict__ dinv,
                                             const unsigned short* __restrict__ xws,
                                             const float* __restrict__ b,
                                             const float* __restrict__ w_s,
                                             const float* __restrict__ w_d,
                                             float* __restrict__ h1f,
                                             unsigned short* __restrict__ h1b,
                                             unsigned short* __restrict__ X,
                                             float4* __restrict__ a_s,
                                             float4* __restrict__ a_d, int n) {
    int t = threadIdx.x, c = t & 63;
    int d = blockIdx.x * 4 + (t >> 6);
    if (d >= n) return;
    int start = row_ptr[d], cnt = hist[d];
    float acc = bf2f(xws[(size_t)d * HID + c]);       // self term
    int k = 0;
    for (; k + 1 < cnt; k += 2) {
        int s0 = col[start + k], s1 = col[start + k + 1];
        float v0 = bf2f(xws[(size_t)s0 * HID + c]);
        float v1 = bf2f(xws[(size_t)s1 * HID + c]);
        acc += v0 + v1;
    }
    if (k < cnt) acc += bf2f(xws[(size_t)col[start + k] * HID + c]);
    float h1c = fmaxf(acc * dinv[d] + b[c], 0.0f);
    h1f[(size_t)d * HID + c] = h1c;
    unsigned short hb = f2bf(h1c);
    h1b[(size_t)d * HID + c] = hb;
    X[(size_t)d * XK + 256 + c] = hb;
    float vs0 = h1c * w_s[c],       vs1 = h1c * w_s[64 + c];
    float vs2 = h1c * w_s[128 + c], vs3 = h1c * w_s[192 + c];
    float vd0 = h1c * w_d[c],       vd1 = h1c * w_d[64 + c];
    float vd2 = h1c * w_d[128 + c], vd3 = h1c * w_d[192 + c];
    for (int o = 32; o > 0; o >>= 1) {
        vs0 += __shfl_xor(vs0, o, 64); vs1 += __shfl_xor(vs1, o, 64);
        vs2 += __shfl_xor(vs2, o, 64); vs3 += __shfl_xor(vs3, o, 64);
        vd0 += __shfl_xor(vd0, o, 64); vd1 += __shfl_xor(vd1, o, 64);
        vd2 += __shfl_xor(vd2, o, 64); vd3 += __shfl_xor(vd3, o, 64);
    }
    if (c == 0) {
        a_s[d] = make_float4(vs0, vs1, vs2, vs3);
        a_d[d] = make_float4(vd0, vd1, vd2, vd3);
    }
}

// ---------- attention aggregation of h1, UNNORMALIZED softmax (logits ~ +-3, exp safe) ----------
// A_h = sum_e exp(e_h)*h1[src]; l_h = sum_e exp(e_h) (wave-uniform, in-register);
// X[d,h,c] = A_h[c]/l_h.  No separate normalizer pass.
__global__ __launch_bounds__(256) void k_attn(const int* __restrict__ col,
                                              const int* __restrict__ row_ptr,
                                              const int* __restrict__ hist,
                                              const float4* __restrict__ a_s,
                                              const float4* __restrict__ a_d,
                                              const unsigned short* __restrict__ h1b,
                                              unsigned short* __restrict__ X, int n) {
    int t = threadIdx.x, c = t & 63;
    int d = blockIdx.x * 4 + (t >> 6);
    if (d >= n) return;
    float4 ad = a_d[d];
    float4 asd = a_s[d];
    // self edge
    float w0 = __expf(leaky(asd.x + ad.x));
    float w1 = __expf(leaky(asd.y + ad.y));
    float w2 = __expf(leaky(asd.z + ad.z));
    float w3 = __expf(leaky(asd.w + ad.w));
    float hs = bf2f(h1b[(size_t)d * HID + c]);
    float A0 = w0 * hs, A1 = w1 * hs, A2 = w2 * hs, A3 = w3 * hs;
    float l0 = w0, l1 = w1, l2 = w2, l3 = w3;
    int start = row_ptr[d], cnt = hist[d];
    int k = 0;
    for (; k + 1 < cnt; k += 2) {
        int s0 = col[start + k], s1 = col[start + k + 1];
        float4 as0 = a_s[s0];
        float4 as1 = a_s[s1];
        float hv0 = bf2f(h1b[(size_t)s0 * HID + c]);
        float hv1 = bf2f(h1b[(size_t)s1 * HID + c]);
        float u0 = __expf(leaky(as0.x + ad.x)), v0 = __expf(leaky(as1.x + ad.x));
        float u1 = __expf(leaky(as0.y + ad.y)), v1 = __expf(leaky(as1.y + ad.y));
        float u2 = __expf(leaky(as0.z + ad.z)), v2 = __expf(leaky(as1.z + ad.z));
        float u3 = __expf(leaky(as0.w + ad.w)), v3 = __expf(leaky(as1.w + ad.w));
        A0 += u0 * hv0 + v0 * hv1; l0 += u0 + v0;
        A1 += u1 * hv0 + v1 * hv1; l1 += u1 + v1;
        A2 += u2 * hv0 + v2 * hv1; l2 += u2 + v2;
        A3 += u3 * hv0 + v3 * hv1; l3 += u3 + v3;
    }
    if (k < cnt) {
        int s0 = col[start + k];
        float4 as0 = a_s[s0];
        float hv0 = bf2f(h1b[(size_t)s0 * HID + c]);
        float u0 = __expf(leaky(as0.x + ad.x));
        float u1 = __expf(leaky(as0.y + ad.y));
        float u2 = __expf(leaky(as0.z + ad.z));
        float u3 = __expf(leaky(as0.w + ad.w));
        A0 += u0 * hv0; l0 += u0;
        A1 += u1 * hv0; l1 += u1;
        A2 += u2 * hv0; l2 += u2;
        A3 += u3 * hv0; l3 += u3;
    }
    size_t base = (size_t)d * XK;
    X[base + c]       = f2bf(A0 / l0);
    X[base + 64 + c]  = f2bf(A1 / l1);
    X[base + 128 + c] = f2bf(A2 / l2);
    X[base + 192 + c] = f2bf(A3 / l3);
}

// ---------- post: MFMA GEMM X[n,320] @ [0.25*Wg' ; Wp] -> agg|hp, + relu/residual/LN ----------
__global__ __launch_bounds__(256) void k_post(const unsigned short* __restrict__ X,
                                              const float* __restrict__ h1f,
                                              const float* __restrict__ Wg,
                                              const float* __restrict__ Wp,
                                              const float* __restrict__ bp,
                                              const float* __restrict__ bg,
                                              const float* __restrict__ gamma,
                                              const float* __restrict__ beta,
                                              float* __restrict__ out, int n) {
    __shared__ unsigned short Wt[40 * 64 * 8];   // 40 KB
    int t = threadIdx.x;
    for (int idx = t; idx < XK * 64; idx += 256) {
        int c = idx & 63, k = idx >> 6;
        float f;
        if (k < 256) f = 0.25f * Wg[(size_t)(k & 63) * 256 + (k >> 6) * 64 + c];
        else         f = Wp[(size_t)(k - 256) * 64 + c];
        Wt[(((k >> 3) * 64) + c) * 8 + (k & 7)] = f2bf(f);
    }
    __syncthreads();

    int lane = t & 63;
    int li = lane & 15, quad = lane >> 4;
    int w = t >> 6;
    int r0 = blockIdx.x * 64 + w * 16;           // 16 rows per wave

    f32x4 acc_a[4], acc_h[4];
#pragma unroll
    for (int i = 0; i < 4; i++) {
        acc_a[i] = (f32x4){0.f, 0.f, 0.f, 0.f};
        acc_h[i] = (f32x4){0.f, 0.f, 0.f, 0.f};
    }
    const unsigned short* xrow = X + (size_t)(r0 + li) * XK + quad * 8;
#pragma unroll
    for (int ks = 0; ks < 10; ks++) {
        bf16x8 a = *(const bf16x8*)(xrow + ks * 32);
        int kg = ks * 4 + quad;
#pragma unroll
        for (int tt = 0; tt < 4; tt++) {
            bf16x8 bfr = *(const bf16x8*)(&Wt[((kg * 64) + tt * 16 + li) * 8]);
            if (ks < 8)
                acc_a[tt] = __builtin_amdgcn_mfma_f32_16x16x32_bf16(a, bfr, acc_a[tt], 0, 0, 0);
            else
                acc_h[tt] = __builtin_amdgcn_mfma_f32_16x16x32_bf16(a, bfr, acc_h[tt], 0, 0, 0);
        }
    }
    float bgv[4], bpv[4], gv[4], btv[4];
#pragma unroll
    for (int tt = 0; tt < 4; tt++) {
        int c = tt * 16 + li;
        bgv[tt] = bg[c]; bpv[tt] = bp[c]; gv[tt] = gamma[c]; btv[tt] = beta[c];
    }
#pragma unroll
    for (int reg = 0; reg < 4; reg++) {
        int r = r0 + quad * 4 + reg;
        bool ok = (r < n);
        float hv[4];
        float s1 = 0.0f, s2 = 0.0f;
#pragma unroll
        for (int tt = 0; tt < 4; tt++) {
            int c = tt * 16 + li;
            float h1c = ok ? h1f[(size_t)r * HID + c] : 0.0f;
            float h2 = fmaxf(acc_a[tt][reg] + bgv[tt], 0.0f);
            float h = h1c + h2 + acc_h[tt][reg] + bpv[tt];
            hv[tt] = h;
            s1 += h; s2 += h * h;
        }
        for (int o = 8; o > 0; o >>= 1) {
            s1 += __shfl_xor(s1, o, 64);
            s2 += __shfl_xor(s2, o, 64);
        }
        float mu = s1 * (1.0f / 64.0f);
        float var = s2 * (1.0f / 64.0f) - mu * mu;
        float rs = rsqrtf(var + LN_EPS);
        if (ok) {
#pragma unroll
            for (int tt = 0; tt < 4; tt++) {
                int c = tt * 16 + li;
                out[(size_t)r * HID + c] = (hv[tt] - mu) * rs * gv[tt] + btv[tt];
            }
        }
    }
}

extern "C" void kernel_launch(void* const* d_in, const int* in_sizes, int n_in,
                              void* d_out, int out_size, void* d_ws, size_t ws_size,
                              hipStream_t stream) {
    int n = in_sizes[0] / IN_DIM;
    int E = in_sizes[1] / 2;

    const float* x     = (const float*)d_in[0];
    const void*  ei    = d_in[1];
    const float* W_gcn = (const float*)d_in[2];
    const float* b_gcn = (const float*)d_in[3];
    const float* W_gat = (const float*)d_in[4];
    const float* att_s = (const float*)d_in[5];
    const float* att_d = (const float*)d_in[6];
    const float* b_gat = (const float*)d_in[7];
    const float* W_p   = (const float*)d_in[8];
    const float* b_p   = (const float*)d_in[9];
    const float* gamma = (const float*)d_in[10];
    const float* beta  = (const float*)d_in[11];

    int n_pad = ((n + 255) / 256) * 256;
    int nscan = n_pad / 256;                 // must be <= 256
    int n64   = ((n + 63) / 64) * 64;        // row padding for MFMA tiles

    float* ws = (float*)d_ws;
    size_t off = 0;
    int*   flag    = (int*)(ws + off);  off += 4;
    int*   edges   = (int*)(ws + off);  off += (size_t)2 * E;
    int*   hist    = (int*)(ws + off);  off += n;
    int*   row_ptr = (int*)(ws + off);  off += n;
    int*   cursor  = (int*)(ws + off);  off += n;
    int*   tmp     = (int*)(ws + off);  off += n_pad;
    int*   partial = (int*)(ws + off);  off += 256;
    int*   colv    = (int*)(ws + off);  off += E;
    float* dinv    = ws + off;          off += n;
    float* w_s     = ws + off;          off += HEADS * HID;
    float* w_d     = ws + off;          off += HEADS * HID;
    off = (off + 3) & ~(size_t)3;
    unsigned short* xws = (unsigned short*)(ws + off); off += (size_t)n * HID / 2;
    float* h1f     = ws + off;          off += (size_t)n * HID;
    off = (off + 3) & ~(size_t)3;
    unsigned short* h1b = (unsigned short*)(ws + off); off += (size_t)n * HID / 2;
    off = (off + 3) & ~(size_t)3;
    float4* a_sv   = (float4*)(ws + off); off += (size_t)n * 4;
    float4* a_dv   = (float4*)(ws + off); off += (size_t)n * 4;
    off = (off + 3) & ~(size_t)3;
    unsigned short* X = (unsigned short*)(ws + off); off += (size_t)n64 * XK / 2;

    const int* src = edges;
    const int* dst = edges + E;

    // detect dtype (block 0) + zero hist
    k_detect_zero<<<(n + 255) / 256, 256, 0, stream>>>(
        (const unsigned long long*)ei, E, n, flag, hist);
    // remap to int32 + dst histogram
    k_remap_hist<<<(2 * E + 255) / 256, 256, 0, stream>>>(ei, E, flag, edges, hist);

    // CSR scan + scatter (+ folded att prep)
    k_scan1<<<nscan, 256, 0, stream>>>(hist, tmp, partial, n);
    k_scan2_prep<<<1, 256, 0, stream>>>(partial, nscan, W_gat, att_s, att_d, w_s, w_d);
    k_scan3<<<nscan, 256, 0, stream>>>(tmp, partial, hist, row_ptr, cursor, dinv, n);
    k_scatter<<<(E + 255) / 256, 256, 0, stream>>>(src, dst, cursor, colv, E);

    // dense GCN projection (bf16, pre-scaled by dinv)
    k_xw<<<(n + 15) / 16, 256, 0, stream>>>(x, W_gcn, dinv, xws, n);

    // GCN gather + logit dots
    k_gcn<<<(n + 3) / 4, 256, 0, stream>>>(colv, row_ptr, hist, dinv, xws, b_gcn,
                                           w_s, w_d, h1f, h1b, X, a_sv, a_dv, n);

    // attention aggregation of h1 -> X cols 0..255 (normalizer fused, no k_mq)
    k_attn<<<(n + 3) / 4, 256, 0, stream>>>(colv, row_ptr, hist, a_sv, a_dv,
                                            h1b, X, n);

    // MFMA post GEMM + relu/residual/LN
    k_post<<<(n + 63) / 64, 256, 0, stream>>>(X, h1f, W_gat, W_p, b_p, b_gat,
                                              gamma, beta, (float*)d_out, n);
}

// Round 8
// 270.680 us; speedup vs baseline: 1.7518x; 1.1162x over previous
//
#include <hip/hip_runtime.h>
#include <math.h>

#define IN_DIM 128
#define HID 64
#define HEADS 4
#define NEG_SLOPE 0.2f
#define LN_EPS 1e-5f
#define XK 320              // stacked K dim: 256 (S) + 64 (h1)

typedef short bf16x8 __attribute__((ext_vector_type(8)));
typedef float f32x4  __attribute__((ext_vector_type(4)));

// ---------- bf16 helpers ----------
__device__ inline unsigned short f2bf(float f) {
    unsigned u = __float_as_uint(f);
    u += 0x7fffu + ((u >> 16) & 1u);     // round-to-nearest-even
    return (unsigned short)(u >> 16);
}
__device__ inline float bf2f(unsigned short s) {
    return __uint_as_float(((unsigned)s) << 16);
}
__device__ inline float leaky(float v) { return v > 0.0f ? v : NEG_SLOPE * v; }

// ---------- zero hist + (block 0) sampled dtype detection ----------
__global__ void k_detect_zero(const unsigned long long* ei, int count, int n,
                              int* flag, int* hist) {
    int i = blockIdx.x * blockDim.x + threadIdx.x;
    if (i < n) hist[i] = 0;
    if (blockIdx.x == 0) {
        __shared__ int s_bad;
        if (threadIdx.x == 0) s_bad = 0;
        __syncthreads();
        int lim = count < 4096 ? count : 4096;
        int bad = 0;
        for (int k = threadIdx.x; k < lim; k += 256)
            if (ei[k] >= (unsigned long long)n) bad = 1;
        if (bad) s_bad = 1;      // benign race
        __syncthreads();
        if (threadIdx.x == 0) *flag = s_bad ? 0 : 1;   // 1 = genuine int64
    }
}

// ---------- remap edge_index to int32 + histogram of dst ----------
__global__ void k_remap_hist(const void* ei, int E, const int* flag,
                             int* edges32, int* hist) {
    int i = blockIdx.x * blockDim.x + threadIdx.x;
    if (i >= 2 * E) return;
    int is64 = *flag;
    int v;
    if (is64) v = (int)((const long long*)ei)[i];
    else      v = ((const int*)ei)[i];
    edges32[i] = v;
    if (i >= E) atomicAdd(&hist[v], 1);    // dst half
}

// ---------- CSR scan ----------
__global__ __launch_bounds__(256) void k_scan1(const int* __restrict__ hist,
                                               int* __restrict__ tmp,
                                               int* __restrict__ partial, int n) {
    __shared__ int s[256];
    int t = threadIdx.x, i = blockIdx.x * 256 + t;
    int v = (i < n) ? hist[i] : 0;
    s[t] = v;
    __syncthreads();
    for (int off = 1; off < 256; off <<= 1) {
        int x = (t >= off) ? s[t - off] : 0;
        __syncthreads();
        s[t] += x;
        __syncthreads();
    }
    tmp[i] = s[t] - v;
    if (t == 255) partial[blockIdx.x] = s[255];
}

// scan of block sums (nb <= 256) + folded att-vector prep
__global__ __launch_bounds__(256) void k_scan2_prep(int* partial, int nb,
                                                    const float* __restrict__ Wg,
                                                    const float* __restrict__ att_s,
                                                    const float* __restrict__ att_d,
                                                    float* __restrict__ w_s,
                                                    float* __restrict__ w_d) {
    __shared__ int s[256];
    int t = threadIdx.x;
    int v = (t < nb) ? partial[t] : 0;
    s[t] = v;
    __syncthreads();
    for (int off = 1; off < 256; off <<= 1) {
        int x = (t >= off) ? s[t - off] : 0;
        __syncthreads();
        s[t] += x;
        __syncthreads();
    }
    if (t < nb) partial[t] = s[t] - v;
    int h = t >> 6, k = t & 63;
    float ss = 0.0f, sd = 0.0f;
    for (int c = 0; c < HID; c++) {
        float w = Wg[(size_t)k * (HEADS * HID) + h * HID + c];
        ss += w * att_s[h * HID + c];
        sd += w * att_d[h * HID + c];
    }
    w_s[h * HID + k] = ss;
    w_d[h * HID + k] = sd;
}

__global__ void k_scan3(const int* __restrict__ tmp, const int* __restrict__ partial,
                        const int* __restrict__ hist, int* __restrict__ row_ptr,
                        int* __restrict__ cursor, float* __restrict__ dinv, int n) {
    int i = blockIdx.x * blockDim.x + threadIdx.x;
    if (i >= n) return;
    int v = tmp[i] + partial[i >> 8];
    row_ptr[i] = v;
    cursor[i] = v;
    dinv[i] = rsqrtf((float)(hist[i] + 1));   // +1 self-loop
}

__global__ void k_scatter(const int* __restrict__ src, const int* __restrict__ dst,
                          int* __restrict__ cursor, int* __restrict__ col, int E) {
    int i = blockIdx.x * blockDim.x + threadIdx.x;
    if (i >= E) return;
    int pos = atomicAdd(&cursor[dst[i]], 1);
    col[pos] = src[i];
}

// ---------- xws = bf16( (x @ W_gcn) * dinv[row] ) via MFMA ----------
// W staged to LDS in [kg][c][8] layout (kg=k>>3): b-frag ds_read_b128 conflict-free.
// A loaded from global f32 x, packed to bf16 in-register. 64 rows/block.
__global__ __launch_bounds__(256) void k_xw(const float* __restrict__ x,
                                            const float* __restrict__ W,
                                            const float* __restrict__ dinv,
                                            unsigned short* __restrict__ xws, int n) {
    __shared__ unsigned short Wt[16 * 64 * 8];   // 16 KB
    int t = threadIdx.x;
    for (int idx = t; idx < IN_DIM * 64; idx += 256) {
        int c = idx & 63, k = idx >> 6;
        Wt[(((k >> 3) * 64) + c) * 8 + (k & 7)] = f2bf(W[(size_t)k * 64 + c]);
    }
    __syncthreads();

    int lane = t & 63;
    int li = lane & 15, quad = lane >> 4;
    int w = t >> 6;
    int r0 = blockIdx.x * 64 + w * 16;
    int rload = r0 + li; if (rload > n - 1) rload = n - 1;   // clamp (discard on store)

    f32x4 acc[4];
#pragma unroll
    for (int i = 0; i < 4; i++) acc[i] = (f32x4){0.f, 0.f, 0.f, 0.f};

    const float* xp = x + (size_t)rload * IN_DIM + quad * 8;
#pragma unroll
    for (int ks = 0; ks < 4; ks++) {
        float4 p0 = *(const float4*)(xp + ks * 32);
        float4 p1 = *(const float4*)(xp + ks * 32 + 4);
        bf16x8 a;
        a[0] = (short)f2bf(p0.x); a[1] = (short)f2bf(p0.y);
        a[2] = (short)f2bf(p0.z); a[3] = (short)f2bf(p0.w);
        a[4] = (short)f2bf(p1.x); a[5] = (short)f2bf(p1.y);
        a[6] = (short)f2bf(p1.z); a[7] = (short)f2bf(p1.w);
        int kg = ks * 4 + quad;
#pragma unroll
        for (int tt = 0; tt < 4; tt++) {
            bf16x8 bfr = *(const bf16x8*)(&Wt[((kg * 64) + tt * 16 + li) * 8]);
            acc[tt] = __builtin_amdgcn_mfma_f32_16x16x32_bf16(a, bfr, acc[tt], 0, 0, 0);
        }
    }
    // C layout: row = r0 + quad*4 + reg, col = tt*16 + li
#pragma unroll
    for (int reg = 0; reg < 4; reg++) {
        int r = r0 + quad * 4 + reg;
        if (r >= n) continue;
        float dv = dinv[r];
#pragma unroll
        for (int tt = 0; tt < 4; tt++) {
            xws[(size_t)r * HID + tt * 16 + li] = f2bf(acc[tt][reg] * dv);
        }
    }
}

// ---------- GCN gather + bias/relu + logit dots; h1 -> f32, compact bf16, X cols 256..319 ----------
__global__ __launch_bounds__(256) void k_gcn(const int* __restrict__ col,
                                             const int* __restrict__ row_ptr,
                                             const int* __restrict__ hist,
                                             const float* __restrict__ dinv,
                                             const unsigned short* __restrict__ xws,
                                             const float* __restrict__ b,
                                             const float* __restrict__ w_s,
                                             const float* __restrict__ w_d,
                                             float* __restrict__ h1f,
                                             unsigned short* __restrict__ h1b,
                                             unsigned short* __restrict__ X,
                                             float4* __restrict__ a_s,
                                             float4* __restrict__ a_d, int n) {
    int t = threadIdx.x, c = t & 63;
    int d = blockIdx.x * 4 + (t >> 6);
    if (d >= n) return;
    int start = row_ptr[d], cnt = hist[d];
    float acc = bf2f(xws[(size_t)d * HID + c]);       // self term
    int k = 0;
    for (; k + 1 < cnt; k += 2) {
        int s0 = col[start + k], s1 = col[start + k + 1];
        float v0 = bf2f(xws[(size_t)s0 * HID + c]);
        float v1 = bf2f(xws[(size_t)s1 * HID + c]);
        acc += v0 + v1;
    }
    if (k < cnt) acc += bf2f(xws[(size_t)col[start + k] * HID + c]);
    float h1c = fmaxf(acc * dinv[d] + b[c], 0.0f);
    h1f[(size_t)d * HID + c] = h1c;
    unsigned short hb = f2bf(h1c);
    h1b[(size_t)d * HID + c] = hb;
    X[(size_t)d * XK + 256 + c] = hb;
    float vs0 = h1c * w_s[c],       vs1 = h1c * w_s[64 + c];
    float vs2 = h1c * w_s[128 + c], vs3 = h1c * w_s[192 + c];
    float vd0 = h1c * w_d[c],       vd1 = h1c * w_d[64 + c];
    float vd2 = h1c * w_d[128 + c], vd3 = h1c * w_d[192 + c];
    for (int o = 32; o > 0; o >>= 1) {
        vs0 += __shfl_xor(vs0, o, 64); vs1 += __shfl_xor(vs1, o, 64);
        vs2 += __shfl_xor(vs2, o, 64); vs3 += __shfl_xor(vs3, o, 64);
        vd0 += __shfl_xor(vd0, o, 64); vd1 += __shfl_xor(vd1, o, 64);
        vd2 += __shfl_xor(vd2, o, 64); vd3 += __shfl_xor(vd3, o, 64);
    }
    if (c == 0) {
        a_s[d] = make_float4(vs0, vs1, vs2, vs3);
        a_d[d] = make_float4(vd0, vd1, vd2, vd3);
    }
}

// ---------- attention aggregation of h1, UNNORMALIZED softmax (logits ~ +-3, exp safe) ----------
__global__ __launch_bounds__(256) void k_attn(const int* __restrict__ col,
                                              const int* __restrict__ row_ptr,
                                              const int* __restrict__ hist,
                                              const float4* __restrict__ a_s,
                                              const float4* __restrict__ a_d,
                                              const unsigned short* __restrict__ h1b,
                                              unsigned short* __restrict__ X, int n) {
    int t = threadIdx.x, c = t & 63;
    int d = blockIdx.x * 4 + (t >> 6);
    if (d >= n) return;
    float4 ad = a_d[d];
    float4 asd = a_s[d];
    float w0 = __expf(leaky(asd.x + ad.x));
    float w1 = __expf(leaky(asd.y + ad.y));
    float w2 = __expf(leaky(asd.z + ad.z));
    float w3 = __expf(leaky(asd.w + ad.w));
    float hs = bf2f(h1b[(size_t)d * HID + c]);
    float A0 = w0 * hs, A1 = w1 * hs, A2 = w2 * hs, A3 = w3 * hs;
    float l0 = w0, l1 = w1, l2 = w2, l3 = w3;
    int start = row_ptr[d], cnt = hist[d];
    int k = 0;
    for (; k + 1 < cnt; k += 2) {
        int s0 = col[start + k], s1 = col[start + k + 1];
        float4 as0 = a_s[s0];
        float4 as1 = a_s[s1];
        float hv0 = bf2f(h1b[(size_t)s0 * HID + c]);
        float hv1 = bf2f(h1b[(size_t)s1 * HID + c]);
        float u0 = __expf(leaky(as0.x + ad.x)), v0 = __expf(leaky(as1.x + ad.x));
        float u1 = __expf(leaky(as0.y + ad.y)), v1 = __expf(leaky(as1.y + ad.y));
        float u2 = __expf(leaky(as0.z + ad.z)), v2 = __expf(leaky(as1.z + ad.z));
        float u3 = __expf(leaky(as0.w + ad.w)), v3 = __expf(leaky(as1.w + ad.w));
        A0 += u0 * hv0 + v0 * hv1; l0 += u0 + v0;
        A1 += u1 * hv0 + v1 * hv1; l1 += u1 + v1;
        A2 += u2 * hv0 + v2 * hv1; l2 += u2 + v2;
        A3 += u3 * hv0 + v3 * hv1; l3 += u3 + v3;
    }
    if (k < cnt) {
        int s0 = col[start + k];
        float4 as0 = a_s[s0];
        float hv0 = bf2f(h1b[(size_t)s0 * HID + c]);
        float u0 = __expf(leaky(as0.x + ad.x));
        float u1 = __expf(leaky(as0.y + ad.y));
        float u2 = __expf(leaky(as0.z + ad.z));
        float u3 = __expf(leaky(as0.w + ad.w));
        A0 += u0 * hv0; l0 += u0;
        A1 += u1 * hv0; l1 += u1;
        A2 += u2 * hv0; l2 += u2;
        A3 += u3 * hv0; l3 += u3;
    }
    size_t base = (size_t)d * XK;
    X[base + c]       = f2bf(A0 / l0);
    X[base + 64 + c]  = f2bf(A1 / l1);
    X[base + 128 + c] = f2bf(A2 / l2);
    X[base + 192 + c] = f2bf(A3 / l3);
}

// ---------- post: MFMA GEMM X[n,320] @ [0.25*Wg' ; Wp] -> agg|hp, + relu/residual/LN ----------
__global__ __launch_bounds__(256) void k_post(const unsigned short* __restrict__ X,
                                              const float* __restrict__ h1f,
                                              const float* __restrict__ Wg,
                                              const float* __restrict__ Wp,
                                              const float* __restrict__ bp,
                                              const float* __restrict__ bg,
                                              const float* __restrict__ gamma,
                                              const float* __restrict__ beta,
                                              float* __restrict__ out, int n) {
    __shared__ unsigned short Wt[40 * 64 * 8];   // 40 KB
    int t = threadIdx.x;
    for (int idx = t; idx < XK * 64; idx += 256) {
        int c = idx & 63, k = idx >> 6;
        float f;
        if (k < 256) f = 0.25f * Wg[(size_t)(k & 63) * 256 + (k >> 6) * 64 + c];
        else         f = Wp[(size_t)(k - 256) * 64 + c];
        Wt[(((k >> 3) * 64) + c) * 8 + (k & 7)] = f2bf(f);
    }
    __syncthreads();

    int lane = t & 63;
    int li = lane & 15, quad = lane >> 4;
    int w = t >> 6;
    int r0 = blockIdx.x * 64 + w * 16;           // 16 rows per wave

    f32x4 acc_a[4], acc_h[4];
#pragma unroll
    for (int i = 0; i < 4; i++) {
        acc_a[i] = (f32x4){0.f, 0.f, 0.f, 0.f};
        acc_h[i] = (f32x4){0.f, 0.f, 0.f, 0.f};
    }
    const unsigned short* xrow = X + (size_t)(r0 + li) * XK + quad * 8;
#pragma unroll
    for (int ks = 0; ks < 10; ks++) {
        bf16x8 a = *(const bf16x8*)(xrow + ks * 32);
        int kg = ks * 4 + quad;
#pragma unroll
        for (int tt = 0; tt < 4; tt++) {
            bf16x8 bfr = *(const bf16x8*)(&Wt[((kg * 64) + tt * 16 + li) * 8]);
            if (ks < 8)
                acc_a[tt] = __builtin_amdgcn_mfma_f32_16x16x32_bf16(a, bfr, acc_a[tt], 0, 0, 0);
            else
                acc_h[tt] = __builtin_amdgcn_mfma_f32_16x16x32_bf16(a, bfr, acc_h[tt], 0, 0, 0);
        }
    }
    float bgv[4], bpv[4], gv[4], btv[4];
#pragma unroll
    for (int tt = 0; tt < 4; tt++) {
        int c = tt * 16 + li;
        bgv[tt] = bg[c]; bpv[tt] = bp[c]; gv[tt] = gamma[c]; btv[tt] = beta[c];
    }
#pragma unroll
    for (int reg = 0; reg < 4; reg++) {
        int r = r0 + quad * 4 + reg;
        bool ok = (r < n);
        float hv[4];
        float s1 = 0.0f, s2 = 0.0f;
#pragma unroll
        for (int tt = 0; tt < 4; tt++) {
            int c = tt * 16 + li;
            float h1c = ok ? h1f[(size_t)r * HID + c] : 0.0f;
            float h2 = fmaxf(acc_a[tt][reg] + bgv[tt], 0.0f);
            float h = h1c + h2 + acc_h[tt][reg] + bpv[tt];
            hv[tt] = h;
            s1 += h; s2 += h * h;
        }
        for (int o = 8; o > 0; o >>= 1) {
            s1 += __shfl_xor(s1, o, 64);
            s2 += __shfl_xor(s2, o, 64);
        }
        float mu = s1 * (1.0f / 64.0f);
        float var = s2 * (1.0f / 64.0f) - mu * mu;
        float rs = rsqrtf(var + LN_EPS);
        if (ok) {
#pragma unroll
            for (int tt = 0; tt < 4; tt++) {
                int c = tt * 16 + li;
                out[(size_t)r * HID + c] = (hv[tt] - mu) * rs * gv[tt] + btv[tt];
            }
        }
    }
}

extern "C" void kernel_launch(void* const* d_in, const int* in_sizes, int n_in,
                              void* d_out, int out_size, void* d_ws, size_t ws_size,
                              hipStream_t stream) {
    int n = in_sizes[0] / IN_DIM;
    int E = in_sizes[1] / 2;

    const float* x     = (const float*)d_in[0];
    const void*  ei    = d_in[1];
    const float* W_gcn = (const float*)d_in[2];
    const float* b_gcn = (const float*)d_in[3];
    const float* W_gat = (const float*)d_in[4];
    const float* att_s = (const float*)d_in[5];
    const float* att_d = (const float*)d_in[6];
    const float* b_gat = (const float*)d_in[7];
    const float* W_p   = (const float*)d_in[8];
    const float* b_p   = (const float*)d_in[9];
    const float* gamma = (const float*)d_in[10];
    const float* beta  = (const float*)d_in[11];

    int n_pad = ((n + 255) / 256) * 256;
    int nscan = n_pad / 256;                 // must be <= 256
    int n64   = ((n + 63) / 64) * 64;        // row padding for MFMA tiles

    float* ws = (float*)d_ws;
    size_t off = 0;
    int*   flag    = (int*)(ws + off);  off += 4;
    int*   edges   = (int*)(ws + off);  off += (size_t)2 * E;
    int*   hist    = (int*)(ws + off);  off += n;
    int*   row_ptr = (int*)(ws + off);  off += n;
    int*   cursor  = (int*)(ws + off);  off += n;
    int*   tmp     = (int*)(ws + off);  off += n_pad;
    int*   partial = (int*)(ws + off);  off += 256;
    int*   colv    = (int*)(ws + off);  off += E;
    float* dinv    = ws + off;          off += n;
    float* w_s     = ws + off;          off += HEADS * HID;
    float* w_d     = ws + off;          off += HEADS * HID;
    off = (off + 3) & ~(size_t)3;
    unsigned short* xws = (unsigned short*)(ws + off); off += (size_t)n * HID / 2;
    float* h1f     = ws + off;          off += (size_t)n * HID;
    off = (off + 3) & ~(size_t)3;
    unsigned short* h1b = (unsigned short*)(ws + off); off += (size_t)n * HID / 2;
    off = (off + 3) & ~(size_t)3;
    float4* a_sv   = (float4*)(ws + off); off += (size_t)n * 4;
    float4* a_dv   = (float4*)(ws + off); off += (size_t)n * 4;
    off = (off + 3) & ~(size_t)3;
    unsigned short* X = (unsigned short*)(ws + off); off += (size_t)n64 * XK / 2;

    const int* src = edges;
    const int* dst = edges + E;

    // detect dtype (block 0) + zero hist
    k_detect_zero<<<(n + 255) / 256, 256, 0, stream>>>(
        (const unsigned long long*)ei, E, n, flag, hist);
    // remap to int32 + dst histogram
    k_remap_hist<<<(2 * E + 255) / 256, 256, 0, stream>>>(ei, E, flag, edges, hist);

    // CSR scan + scatter (+ folded att prep)
    k_scan1<<<nscan, 256, 0, stream>>>(hist, tmp, partial, n);
    k_scan2_prep<<<1, 256, 0, stream>>>(partial, nscan, W_gat, att_s, att_d, w_s, w_d);
    k_scan3<<<nscan, 256, 0, stream>>>(tmp, partial, hist, row_ptr, cursor, dinv, n);
    k_scatter<<<(E + 255) / 256, 256, 0, stream>>>(src, dst, cursor, colv, E);

    // dense GCN projection via MFMA (bf16, pre-scaled by dinv)
    k_xw<<<(n + 63) / 64, 256, 0, stream>>>(x, W_gcn, dinv, xws, n);

    // GCN gather + logit dots
    k_gcn<<<(n + 3) / 4, 256, 0, stream>>>(colv, row_ptr, hist, dinv, xws, b_gcn,
                                           w_s, w_d, h1f, h1b, X, a_sv, a_dv, n);

    // attention aggregation of h1 -> X cols 0..255 (normalizer fused, no k_mq)
    k_attn<<<(n + 3) / 4, 256, 0, stream>>>(colv, row_ptr, hist, a_sv, a_dv,
                                            h1b, X, n);

    // MFMA post GEMM + relu/residual/LN
    k_post<<<(n + 63) / 64, 256, 0, stream>>>(X, h1f, W_gat, W_p, b_p, b_gat,
                                              gamma, beta, (float*)d_out, n);
}

// Round 9
// 263.522 us; speedup vs baseline: 1.7994x; 1.0272x over previous
//
#include <hip/hip_runtime.h>
#include <math.h>

#define IN_DIM 128
#define HID 64
#define HEADS 4
#define NEG_SLOPE 0.2f
#define LN_EPS 1e-5f
#define XK 320              // stacked K dim: 256 (S) + 64 (h1)

typedef short bf16x8 __attribute__((ext_vector_type(8)));
typedef float f32x4  __attribute__((ext_vector_type(4)));

// ---------- bf16 helpers ----------
__device__ inline unsigned short f2bf(float f) {
    unsigned u = __float_as_uint(f);
    u += 0x7fffu + ((u >> 16) & 1u);     // round-to-nearest-even
    return (unsigned short)(u >> 16);
}
__device__ inline float bf2f(unsigned short s) {
    return __uint_as_float(((unsigned)s) << 16);
}
__device__ inline float leaky(float v) { return v > 0.0f ? v : NEG_SLOPE * v; }

// ---------- zero hist + (block 0) sampled dtype detection ----------
__global__ void k_detect_zero(const unsigned long long* ei, int count, int n,
                              int* flag, int* hist) {
    int i = blockIdx.x * blockDim.x + threadIdx.x;
    if (i < n) hist[i] = 0;
    if (blockIdx.x == 0) {
        __shared__ int s_bad;
        if (threadIdx.x == 0) s_bad = 0;
        __syncthreads();
        int lim = count < 4096 ? count : 4096;
        int bad = 0;
        for (int k = threadIdx.x; k < lim; k += 256)
            if (ei[k] >= (unsigned long long)n) bad = 1;
        if (bad) s_bad = 1;      // benign race
        __syncthreads();
        if (threadIdx.x == 0) *flag = s_bad ? 0 : 1;   // 1 = genuine int64
    }
}

// ---------- remap edge_index to int32 + histogram of dst ----------
__global__ void k_remap_hist(const void* ei, int E, const int* flag,
                             int* edges32, int* hist) {
    int i = blockIdx.x * blockDim.x + threadIdx.x;
    if (i >= 2 * E) return;
    int is64 = *flag;
    int v;
    if (is64) v = (int)((const long long*)ei)[i];
    else      v = ((const int*)ei)[i];
    edges32[i] = v;
    if (i >= E) atomicAdd(&hist[v], 1);    // dst half
}

// ---------- CSR scan ----------
__global__ __launch_bounds__(256) void k_scan1(const int* __restrict__ hist,
                                               int* __restrict__ tmp,
                                               int* __restrict__ partial, int n) {
    __shared__ int s[256];
    int t = threadIdx.x, i = blockIdx.x * 256 + t;
    int v = (i < n) ? hist[i] : 0;
    s[t] = v;
    __syncthreads();
    for (int off = 1; off < 256; off <<= 1) {
        int x = (t >= off) ? s[t - off] : 0;
        __syncthreads();
        s[t] += x;
        __syncthreads();
    }
    tmp[i] = s[t] - v;
    if (t == 255) partial[blockIdx.x] = s[255];
}

// scan of block sums (nb <= 256) + folded att-vector prep
__global__ __launch_bounds__(256) void k_scan2_prep(int* partial, int nb,
                                                    const float* __restrict__ Wg,
                                                    const float* __restrict__ att_s,
                                                    const float* __restrict__ att_d,
                                                    float* __restrict__ w_s,
                                                    float* __restrict__ w_d) {
    __shared__ int s[256];
    int t = threadIdx.x;
    int v = (t < nb) ? partial[t] : 0;
    s[t] = v;
    __syncthreads();
    for (int off = 1; off < 256; off <<= 1) {
        int x = (t >= off) ? s[t - off] : 0;
        __syncthreads();
        s[t] += x;
        __syncthreads();
    }
    if (t < nb) partial[t] = s[t] - v;
    int h = t >> 6, k = t & 63;
    float ss = 0.0f, sd = 0.0f;
    for (int c = 0; c < HID; c++) {
        float w = Wg[(size_t)k * (HEADS * HID) + h * HID + c];
        ss += w * att_s[h * HID + c];
        sd += w * att_d[h * HID + c];
    }
    w_s[h * HID + k] = ss;
    w_d[h * HID + k] = sd;
}

__global__ void k_scan3(const int* __restrict__ tmp, const int* __restrict__ partial,
                        const int* __restrict__ hist, int* __restrict__ row_ptr,
                        int* __restrict__ cursor, float* __restrict__ dinv, int n) {
    int i = blockIdx.x * blockDim.x + threadIdx.x;
    if (i >= n) return;
    int v = tmp[i] + partial[i >> 8];
    row_ptr[i] = v;
    cursor[i] = v;
    dinv[i] = rsqrtf((float)(hist[i] + 1));   // +1 self-loop
}

__global__ void k_scatter(const int* __restrict__ src, const int* __restrict__ dst,
                          int* __restrict__ cursor, int* __restrict__ col,
                          int* __restrict__ col_d, int E) {
    int i = blockIdx.x * blockDim.x + threadIdx.x;
    if (i >= E) return;
    int d = dst[i];
    int pos = atomicAdd(&cursor[d], 1);
    col[pos] = src[i];
    col_d[pos] = d;
}

// ---------- xws = bf16( (x @ W_gcn) * dinv[row] ) via MFMA ----------
__global__ __launch_bounds__(256) void k_xw(const float* __restrict__ x,
                                            const float* __restrict__ W,
                                            const float* __restrict__ dinv,
                                            unsigned short* __restrict__ xws, int n) {
    __shared__ unsigned short Wt[16 * 64 * 8];   // 16 KB
    int t = threadIdx.x;
    for (int idx = t; idx < IN_DIM * 64; idx += 256) {
        int c = idx & 63, k = idx >> 6;
        Wt[(((k >> 3) * 64) + c) * 8 + (k & 7)] = f2bf(W[(size_t)k * 64 + c]);
    }
    __syncthreads();

    int lane = t & 63;
    int li = lane & 15, quad = lane >> 4;
    int w = t >> 6;
    int r0 = blockIdx.x * 64 + w * 16;
    int rload = r0 + li; if (rload > n - 1) rload = n - 1;   // clamp (discard on store)

    f32x4 acc[4];
#pragma unroll
    for (int i = 0; i < 4; i++) acc[i] = (f32x4){0.f, 0.f, 0.f, 0.f};

    const float* xp = x + (size_t)rload * IN_DIM + quad * 8;
#pragma unroll
    for (int ks = 0; ks < 4; ks++) {
        float4 p0 = *(const float4*)(xp + ks * 32);
        float4 p1 = *(const float4*)(xp + ks * 32 + 4);
        bf16x8 a;
        a[0] = (short)f2bf(p0.x); a[1] = (short)f2bf(p0.y);
        a[2] = (short)f2bf(p0.z); a[3] = (short)f2bf(p0.w);
        a[4] = (short)f2bf(p1.x); a[5] = (short)f2bf(p1.y);
        a[6] = (short)f2bf(p1.z); a[7] = (short)f2bf(p1.w);
        int kg = ks * 4 + quad;
#pragma unroll
        for (int tt = 0; tt < 4; tt++) {
            bf16x8 bfr = *(const bf16x8*)(&Wt[((kg * 64) + tt * 16 + li) * 8]);
            acc[tt] = __builtin_amdgcn_mfma_f32_16x16x32_bf16(a, bfr, acc[tt], 0, 0, 0);
        }
    }
#pragma unroll
    for (int reg = 0; reg < 4; reg++) {
        int r = r0 + quad * 4 + reg;
        if (r >= n) continue;
        float dv = dinv[r];
#pragma unroll
        for (int tt = 0; tt < 4; tt++) {
            xws[(size_t)r * HID + tt * 16 + li] = f2bf(acc[tt][reg] * dv);
        }
    }
}

// ---------- GCN gather + bias/relu + logit dots ----------
__global__ __launch_bounds__(256) void k_gcn(const int* __restrict__ col,
                                             const int* __restrict__ row_ptr,
                                             const int* __restrict__ hist,
                                             const float* __restrict__ dinv,
                                             const unsigned short* __restrict__ xws,
                                             const float* __restrict__ b,
                                             const float* __restrict__ w_s,
                                             const float* __restrict__ w_d,
                                             float* __restrict__ h1f,
                                             unsigned short* __restrict__ h1b,
                                             unsigned short* __restrict__ X,
                                             float4* __restrict__ a_s,
                                             float4* __restrict__ a_d, int n) {
    int t = threadIdx.x, c = t & 63;
    int d = blockIdx.x * 4 + (t >> 6);
    if (d >= n) return;
    int start = row_ptr[d], cnt = hist[d];
    float acc = bf2f(xws[(size_t)d * HID + c]);       // self term
    int k = 0;
    for (; k + 3 < cnt; k += 4) {
        int s0 = col[start + k],     s1 = col[start + k + 1];
        int s2 = col[start + k + 2], s3 = col[start + k + 3];
        float v0 = bf2f(xws[(size_t)s0 * HID + c]);
        float v1 = bf2f(xws[(size_t)s1 * HID + c]);
        float v2 = bf2f(xws[(size_t)s2 * HID + c]);
        float v3 = bf2f(xws[(size_t)s3 * HID + c]);
        acc += (v0 + v1) + (v2 + v3);
    }
    for (; k < cnt; k++) acc += bf2f(xws[(size_t)col[start + k] * HID + c]);
    float h1c = fmaxf(acc * dinv[d] + b[c], 0.0f);
    h1f[(size_t)d * HID + c] = h1c;
    unsigned short hb = f2bf(h1c);
    h1b[(size_t)d * HID + c] = hb;
    X[(size_t)d * XK + 256 + c] = hb;
    float vs0 = h1c * w_s[c],       vs1 = h1c * w_s[64 + c];
    float vs2 = h1c * w_s[128 + c], vs3 = h1c * w_s[192 + c];
    float vd0 = h1c * w_d[c],       vd1 = h1c * w_d[64 + c];
    float vd2 = h1c * w_d[128 + c], vd3 = h1c * w_d[192 + c];
    for (int o = 32; o > 0; o >>= 1) {
        vs0 += __shfl_xor(vs0, o, 64); vs1 += __shfl_xor(vs1, o, 64);
        vs2 += __shfl_xor(vs2, o, 64); vs3 += __shfl_xor(vs3, o, 64);
        vd0 += __shfl_xor(vd0, o, 64); vd1 += __shfl_xor(vd1, o, 64);
        vd2 += __shfl_xor(vd2, o, 64); vd3 += __shfl_xor(vd3, o, 64);
    }
    if (c == 0) {
        a_s[d] = make_float4(vs0, vs1, vs2, vs3);
        a_d[d] = make_float4(vd0, vd1, vd2, vd3);
    }
}

// ---------- per-edge softmax weights (edge-parallel, not per-lane-replicated) ----------
__global__ void k_ew(const int* __restrict__ col, const int* __restrict__ col_d,
                     const float4* __restrict__ a_s, const float4* __restrict__ a_d,
                     float4* __restrict__ wbuf, int E) {
    int i = blockIdx.x * blockDim.x + threadIdx.x;
    if (i >= E) return;
    int s = col[i], d = col_d[i];
    float4 as = a_s[s], ad = a_d[d];
    float4 r;
    r.x = __expf(leaky(as.x + ad.x));
    r.y = __expf(leaky(as.y + ad.y));
    r.z = __expf(leaky(as.z + ad.z));
    r.w = __expf(leaky(as.w + ad.w));
    wbuf[i] = r;
}

// ---------- attention aggregation of h1 with precomputed weights ----------
__global__ __launch_bounds__(256) void k_attn(const int* __restrict__ col,
                                              const int* __restrict__ row_ptr,
                                              const int* __restrict__ hist,
                                              const float4* __restrict__ a_s,
                                              const float4* __restrict__ a_d,
                                              const float4* __restrict__ wbuf,
                                              const unsigned short* __restrict__ h1b,
                                              unsigned short* __restrict__ X, int n) {
    int t = threadIdx.x, c = t & 63;
    int d = blockIdx.x * 4 + (t >> 6);
    if (d >= n) return;
    float4 ad = a_d[d];
    float4 asd = a_s[d];
    // self edge
    float w0 = __expf(leaky(asd.x + ad.x));
    float w1 = __expf(leaky(asd.y + ad.y));
    float w2 = __expf(leaky(asd.z + ad.z));
    float w3 = __expf(leaky(asd.w + ad.w));
    float hs = bf2f(h1b[(size_t)d * HID + c]);
    float A0 = w0 * hs, A1 = w1 * hs, A2 = w2 * hs, A3 = w3 * hs;
    float l0 = w0, l1 = w1, l2 = w2, l3 = w3;
    int start = row_ptr[d], cnt = hist[d];
    int k = 0;
    for (; k + 3 < cnt; k += 4) {
        int s0 = col[start + k],     s1 = col[start + k + 1];
        int s2 = col[start + k + 2], s3 = col[start + k + 3];
        float4 e0 = wbuf[start + k],     e1 = wbuf[start + k + 1];
        float4 e2 = wbuf[start + k + 2], e3 = wbuf[start + k + 3];
        float hv0 = bf2f(h1b[(size_t)s0 * HID + c]);
        float hv1 = bf2f(h1b[(size_t)s1 * HID + c]);
        float hv2 = bf2f(h1b[(size_t)s2 * HID + c]);
        float hv3 = bf2f(h1b[(size_t)s3 * HID + c]);
        A0 += e0.x * hv0 + e1.x * hv1 + e2.x * hv2 + e3.x * hv3;
        A1 += e0.y * hv0 + e1.y * hv1 + e2.y * hv2 + e3.y * hv3;
        A2 += e0.z * hv0 + e1.z * hv1 + e2.z * hv2 + e3.z * hv3;
        A3 += e0.w * hv0 + e1.w * hv1 + e2.w * hv2 + e3.w * hv3;
        l0 += (e0.x + e1.x) + (e2.x + e3.x);
        l1 += (e0.y + e1.y) + (e2.y + e3.y);
        l2 += (e0.z + e1.z) + (e2.z + e3.z);
        l3 += (e0.w + e1.w) + (e2.w + e3.w);
    }
    for (; k < cnt; k++) {
        int s0 = col[start + k];
        float4 e0 = wbuf[start + k];
        float hv0 = bf2f(h1b[(size_t)s0 * HID + c]);
        A0 += e0.x * hv0; l0 += e0.x;
        A1 += e0.y * hv0; l1 += e0.y;
        A2 += e0.z * hv0; l2 += e0.z;
        A3 += e0.w * hv0; l3 += e0.w;
    }
    size_t base = (size_t)d * XK;
    X[base + c]       = f2bf(A0 / l0);
    X[base + 64 + c]  = f2bf(A1 / l1);
    X[base + 128 + c] = f2bf(A2 / l2);
    X[base + 192 + c] = f2bf(A3 / l3);
}

// ---------- post: MFMA GEMM X[n,320] @ [0.25*Wg' ; Wp] -> agg|hp, + relu/residual/LN ----------
__global__ __launch_bounds__(256) void k_post(const unsigned short* __restrict__ X,
                                              const float* __restrict__ h1f,
                                              const float* __restrict__ Wg,
                                              const float* __restrict__ Wp,
                                              const float* __restrict__ bp,
                                              const float* __restrict__ bg,
                                              const float* __restrict__ gamma,
                                              const float* __restrict__ beta,
                                              float* __restrict__ out, int n) {
    __shared__ unsigned short Wt[40 * 64 * 8];   // 40 KB
    int t = threadIdx.x;
    for (int idx = t; idx < XK * 64; idx += 256) {
        int c = idx & 63, k = idx >> 6;
        float f;
        if (k < 256) f = 0.25f * Wg[(size_t)(k & 63) * 256 + (k >> 6) * 64 + c];
        else         f = Wp[(size_t)(k - 256) * 64 + c];
        Wt[(((k >> 3) * 64) + c) * 8 + (k & 7)] = f2bf(f);
    }
    __syncthreads();

    int lane = t & 63;
    int li = lane & 15, quad = lane >> 4;
    int w = t >> 6;
    int r0 = blockIdx.x * 64 + w * 16;           // 16 rows per wave

    f32x4 acc_a[4], acc_h[4];
#pragma unroll
    for (int i = 0; i < 4; i++) {
        acc_a[i] = (f32x4){0.f, 0.f, 0.f, 0.f};
        acc_h[i] = (f32x4){0.f, 0.f, 0.f, 0.f};
    }
    const unsigned short* xrow = X + (size_t)(r0 + li) * XK + quad * 8;
#pragma unroll
    for (int ks = 0; ks < 10; ks++) {
        bf16x8 a = *(const bf16x8*)(xrow + ks * 32);
        int kg = ks * 4 + quad;
#pragma unroll
        for (int tt = 0; tt < 4; tt++) {
            bf16x8 bfr = *(const bf16x8*)(&Wt[((kg * 64) + tt * 16 + li) * 8]);
            if (ks < 8)
                acc_a[tt] = __builtin_amdgcn_mfma_f32_16x16x32_bf16(a, bfr, acc_a[tt], 0, 0, 0);
            else
                acc_h[tt] = __builtin_amdgcn_mfma_f32_16x16x32_bf16(a, bfr, acc_h[tt], 0, 0, 0);
        }
    }
    float bgv[4], bpv[4], gv[4], btv[4];
#pragma unroll
    for (int tt = 0; tt < 4; tt++) {
        int c = tt * 16 + li;
        bgv[tt] = bg[c]; bpv[tt] = bp[c]; gv[tt] = gamma[c]; btv[tt] = beta[c];
    }
#pragma unroll
    for (int reg = 0; reg < 4; reg++) {
        int r = r0 + quad * 4 + reg;
        bool ok = (r < n);
        float hv[4];
        float s1 = 0.0f, s2 = 0.0f;
#pragma unroll
        for (int tt = 0; tt < 4; tt++) {
            int c = tt * 16 + li;
            float h1c = ok ? h1f[(size_t)r * HID + c] : 0.0f;
            float h2 = fmaxf(acc_a[tt][reg] + bgv[tt], 0.0f);
            float h = h1c + h2 + acc_h[tt][reg] + bpv[tt];
            hv[tt] = h;
            s1 += h; s2 += h * h;
        }
        for (int o = 8; o > 0; o >>= 1) {
            s1 += __shfl_xor(s1, o, 64);
            s2 += __shfl_xor(s2, o, 64);
        }
        float mu = s1 * (1.0f / 64.0f);
        float var = s2 * (1.0f / 64.0f) - mu * mu;
        float rs = rsqrtf(var + LN_EPS);
        if (ok) {
#pragma unroll
            for (int tt = 0; tt < 4; tt++) {
                int c = tt * 16 + li;
                out[(size_t)r * HID + c] = (hv[tt] - mu) * rs * gv[tt] + btv[tt];
            }
        }
    }
}

extern "C" void kernel_launch(void* const* d_in, const int* in_sizes, int n_in,
                              void* d_out, int out_size, void* d_ws, size_t ws_size,
                              hipStream_t stream) {
    int n = in_sizes[0] / IN_DIM;
    int E = in_sizes[1] / 2;

    const float* x     = (const float*)d_in[0];
    const void*  ei    = d_in[1];
    const float* W_gcn = (const float*)d_in[2];
    const float* b_gcn = (const float*)d_in[3];
    const float* W_gat = (const float*)d_in[4];
    const float* att_s = (const float*)d_in[5];
    const float* att_d = (const float*)d_in[6];
    const float* b_gat = (const float*)d_in[7];
    const float* W_p   = (const float*)d_in[8];
    const float* b_p   = (const float*)d_in[9];
    const float* gamma = (const float*)d_in[10];
    const float* beta  = (const float*)d_in[11];

    int n_pad = ((n + 255) / 256) * 256;
    int nscan = n_pad / 256;                 // must be <= 256
    int n64   = ((n + 63) / 64) * 64;        // row padding for MFMA tiles

    float* ws = (float*)d_ws;
    size_t off = 0;
    int*   flag    = (int*)(ws + off);  off += 4;
    int*   edges   = (int*)(ws + off);  off += (size_t)2 * E;
    int*   hist    = (int*)(ws + off);  off += n;
    int*   row_ptr = (int*)(ws + off);  off += n;
    int*   cursor  = (int*)(ws + off);  off += n;
    int*   tmp     = (int*)(ws + off);  off += n_pad;
    int*   partial = (int*)(ws + off);  off += 256;
    int*   colv    = (int*)(ws + off);  off += E;
    int*   col_d   = (int*)(ws + off);  off += E;
    float* dinv    = ws + off;          off += n;
    float* w_s     = ws + off;          off += HEADS * HID;
    float* w_d     = ws + off;          off += HEADS * HID;
    off = (off + 3) & ~(size_t)3;
    unsigned short* xws = (unsigned short*)(ws + off); off += (size_t)n * HID / 2;
    float* h1f     = ws + off;          off += (size_t)n * HID;
    off = (off + 3) & ~(size_t)3;
    unsigned short* h1b = (unsigned short*)(ws + off); off += (size_t)n * HID / 2;
    off = (off + 3) & ~(size_t)3;
    float4* a_sv   = (float4*)(ws + off); off += (size_t)n * 4;
    float4* a_dv   = (float4*)(ws + off); off += (size_t)n * 4;
    off = (off + 3) & ~(size_t)3;
    float4* wbuf   = (float4*)(ws + off); off += (size_t)E * 4;
    unsigned short* X = (unsigned short*)(ws + off); off += (size_t)n64 * XK / 2;

    const int* src = edges;
    const int* dst = edges + E;

    // detect dtype (block 0) + zero hist
    k_detect_zero<<<(n + 255) / 256, 256, 0, stream>>>(
        (const unsigned long long*)ei, E, n, flag, hist);
    // remap to int32 + dst histogram
    k_remap_hist<<<(2 * E + 255) / 256, 256, 0, stream>>>(ei, E, flag, edges, hist);

    // CSR scan + scatter (+ folded att prep)
    k_scan1<<<nscan, 256, 0, stream>>>(hist, tmp, partial, n);
    k_scan2_prep<<<1, 256, 0, stream>>>(partial, nscan, W_gat, att_s, att_d, w_s, w_d);
    k_scan3<<<nscan, 256, 0, stream>>>(tmp, partial, hist, row_ptr, cursor, dinv, n);
    k_scatter<<<(E + 255) / 256, 256, 0, stream>>>(src, dst, cursor, colv, col_d, E);

    // dense GCN projection via MFMA (bf16, pre-scaled by dinv)
    k_xw<<<(n + 63) / 64, 256, 0, stream>>>(x, W_gcn, dinv, xws, n);

    // GCN gather + logit dots
    k_gcn<<<(n + 3) / 4, 256, 0, stream>>>(colv, row_ptr, hist, dinv, xws, b_gcn,
                                           w_s, w_d, h1f, h1b, X, a_sv, a_dv, n);

    // per-edge softmax weights (edge-parallel exp)
    k_ew<<<(E + 255) / 256, 256, 0, stream>>>(colv, col_d, a_sv, a_dv, wbuf, E);

    // attention aggregation of h1 -> X cols 0..255
    k_attn<<<(n + 3) / 4, 256, 0, stream>>>(colv, row_ptr, hist, a_sv, a_dv,
                                            wbuf, h1b, X, n);

    // MFMA post GEMM + relu/residual/LN
    k_post<<<(n + 63) / 64, 256, 0, stream>>>(X, h1f, W_gat, W_p, b_p, b_gat,
                                              gamma, beta, (float*)d_out, n);
}

// Round 10
// 244.536 us; speedup vs baseline: 1.9391x; 1.0776x over previous
//
#include <hip/hip_runtime.h>
#include <math.h>

#define IN_DIM 128
#define HID 64
#define HEADS 4
#define NEG_SLOPE 0.2f
#define LN_EPS 1e-5f
#define XK 320              // stacked K dim: 256 (S) + 64 (h1)

typedef short bf16x8 __attribute__((ext_vector_type(8)));
typedef float f32x4  __attribute__((ext_vector_type(4)));

// ---------- bf16 helpers ----------
__device__ inline unsigned short f2bf(float f) {
    unsigned u = __float_as_uint(f);
    u += 0x7fffu + ((u >> 16) & 1u);     // round-to-nearest-even
    return (unsigned short)(u >> 16);
}
__device__ inline float bf2f(unsigned short s) {
    return __uint_as_float(((unsigned)s) << 16);
}
__device__ inline float leaky(float v) { return v > 0.0f ? v : NEG_SLOPE * v; }

// ---------- zero hist + (block 0) sampled dtype detection ----------
__global__ void k_detect_zero(const unsigned long long* ei, int count, int n,
                              int* flag, int* hist) {
    int i = blockIdx.x * blockDim.x + threadIdx.x;
    if (i < n) hist[i] = 0;
    if (blockIdx.x == 0) {
        __shared__ int s_bad;
        if (threadIdx.x == 0) s_bad = 0;
        __syncthreads();
        int lim = count < 4096 ? count : 4096;
        int bad = 0;
        for (int k = threadIdx.x; k < lim; k += 256)
            if (ei[k] >= (unsigned long long)n) bad = 1;
        if (bad) s_bad = 1;      // benign race
        __syncthreads();
        if (threadIdx.x == 0) *flag = s_bad ? 0 : 1;   // 1 = genuine int64
    }
}

// ---------- pre-pack weights into MFMA-ready [kg][c][8] bf16 layout (global) ----------
// Wt_post: 2560 groups (kg<32: 0.25*Wg', kg>=32: Wp); Wt_xw: 1024 groups (W_gcn).
__global__ void k_wprep(const float* __restrict__ Wg, const float* __restrict__ Wp,
                        const float* __restrict__ Wgcn,
                        unsigned short* __restrict__ Wt_post,
                        unsigned short* __restrict__ Wt_xw) {
    int p = blockIdx.x * 256 + threadIdx.x;
    if (p < 2560) {
        int c = p & 63, kg = p >> 6;
        bf16x8 v;
#pragma unroll
        for (int j = 0; j < 8; j++) {
            int k = kg * 8 + j;
            float f;
            if (k < 256) f = 0.25f * Wg[(size_t)(k & 63) * 256 + (k >> 6) * 64 + c];
            else         f = Wp[(size_t)(k - 256) * 64 + c];
            v[j] = (short)f2bf(f);
        }
        *(bf16x8*)(&Wt_post[(size_t)p * 8]) = v;
    } else if (p < 2560 + 1024) {
        int q = p - 2560;
        int c = q & 63, kg = q >> 6;
        bf16x8 v;
#pragma unroll
        for (int j = 0; j < 8; j++)
            v[j] = (short)f2bf(Wgcn[(size_t)(kg * 8 + j) * 64 + c]);
        *(bf16x8*)(&Wt_xw[(size_t)q * 8]) = v;
    }
}

// ---------- remap edge_index to int32 + histogram of dst ----------
__global__ void k_remap_hist(const void* ei, int E, const int* flag,
                             int* edges32, int* hist) {
    int i = blockIdx.x * blockDim.x + threadIdx.x;
    if (i >= 2 * E) return;
    int is64 = *flag;
    int v;
    if (is64) v = (int)((const long long*)ei)[i];
    else      v = ((const int*)ei)[i];
    edges32[i] = v;
    if (i >= E) atomicAdd(&hist[v], 1);    // dst half
}

// ---------- CSR scan ----------
__global__ __launch_bounds__(256) void k_scan1(const int* __restrict__ hist,
                                               int* __restrict__ tmp,
                                               int* __restrict__ partial, int n) {
    __shared__ int s[256];
    int t = threadIdx.x, i = blockIdx.x * 256 + t;
    int v = (i < n) ? hist[i] : 0;
    s[t] = v;
    __syncthreads();
    for (int off = 1; off < 256; off <<= 1) {
        int x = (t >= off) ? s[t - off] : 0;
        __syncthreads();
        s[t] += x;
        __syncthreads();
    }
    tmp[i] = s[t] - v;
    if (t == 255) partial[blockIdx.x] = s[255];
}

// scan of block sums (nb <= 256) + folded att-vector prep
__global__ __launch_bounds__(256) void k_scan2_prep(int* partial, int nb,
                                                    const float* __restrict__ Wg,
                                                    const float* __restrict__ att_s,
                                                    const float* __restrict__ att_d,
                                                    float* __restrict__ w_s,
                                                    float* __restrict__ w_d) {
    __shared__ int s[256];
    int t = threadIdx.x;
    int v = (t < nb) ? partial[t] : 0;
    s[t] = v;
    __syncthreads();
    for (int off = 1; off < 256; off <<= 1) {
        int x = (t >= off) ? s[t - off] : 0;
        __syncthreads();
        s[t] += x;
        __syncthreads();
    }
    if (t < nb) partial[t] = s[t] - v;
    int h = t >> 6, k = t & 63;
    float ss = 0.0f, sd = 0.0f;
    for (int c = 0; c < HID; c++) {
        float w = Wg[(size_t)k * (HEADS * HID) + h * HID + c];
        ss += w * att_s[h * HID + c];
        sd += w * att_d[h * HID + c];
    }
    w_s[h * HID + k] = ss;
    w_d[h * HID + k] = sd;
}

__global__ void k_scan3(const int* __restrict__ tmp, const int* __restrict__ partial,
                        const int* __restrict__ hist, int* __restrict__ row_ptr,
                        int* __restrict__ cursor, float* __restrict__ dinv, int n) {
    int i = blockIdx.x * blockDim.x + threadIdx.x;
    if (i >= n) return;
    int v = tmp[i] + partial[i >> 8];
    row_ptr[i] = v;
    cursor[i] = v;
    dinv[i] = rsqrtf((float)(hist[i] + 1));   // +1 self-loop
}

__global__ void k_scatter(const int* __restrict__ src, const int* __restrict__ dst,
                          int* __restrict__ cursor, int* __restrict__ col,
                          int* __restrict__ col_d, int E) {
    int i = blockIdx.x * blockDim.x + threadIdx.x;
    if (i >= E) return;
    int d = dst[i];
    int pos = atomicAdd(&cursor[d], 1);
    col[pos] = src[i];
    col_d[pos] = d;
}

// ---------- xws = bf16( (x @ W_gcn) * dinv[row] ) via MFMA ----------
__global__ __launch_bounds__(256) void k_xw(const float* __restrict__ x,
                                            const unsigned short* __restrict__ Wt_g,
                                            const float* __restrict__ dinv,
                                            unsigned short* __restrict__ xws, int n) {
    __shared__ unsigned short Wt[16 * 64 * 8];   // 16 KB
    int t = threadIdx.x;
    for (int idx = t; idx < 1024; idx += 256)    // contiguous copy, conflict-free
        *(bf16x8*)(&Wt[idx * 8]) = *(const bf16x8*)(&Wt_g[(size_t)idx * 8]);
    __syncthreads();

    int lane = t & 63;
    int li = lane & 15, quad = lane >> 4;
    int w = t >> 6;
    int r0 = blockIdx.x * 64 + w * 16;
    int rload = r0 + li; if (rload > n - 1) rload = n - 1;   // clamp (discard on store)

    f32x4 acc[4];
#pragma unroll
    for (int i = 0; i < 4; i++) acc[i] = (f32x4){0.f, 0.f, 0.f, 0.f};

    const float* xp = x + (size_t)rload * IN_DIM + quad * 8;
#pragma unroll
    for (int ks = 0; ks < 4; ks++) {
        float4 p0 = *(const float4*)(xp + ks * 32);
        float4 p1 = *(const float4*)(xp + ks * 32 + 4);
        bf16x8 a;
        a[0] = (short)f2bf(p0.x); a[1] = (short)f2bf(p0.y);
        a[2] = (short)f2bf(p0.z); a[3] = (short)f2bf(p0.w);
        a[4] = (short)f2bf(p1.x); a[5] = (short)f2bf(p1.y);
        a[6] = (short)f2bf(p1.z); a[7] = (short)f2bf(p1.w);
        int kg = ks * 4 + quad;
#pragma unroll
        for (int tt = 0; tt < 4; tt++) {
            bf16x8 bfr = *(const bf16x8*)(&Wt[((kg * 64) + tt * 16 + li) * 8]);
            acc[tt] = __builtin_amdgcn_mfma_f32_16x16x32_bf16(a, bfr, acc[tt], 0, 0, 0);
        }
    }
#pragma unroll
    for (int reg = 0; reg < 4; reg++) {
        int r = r0 + quad * 4 + reg;
        if (r >= n) continue;
        float dv = dinv[r];
#pragma unroll
        for (int tt = 0; tt < 4; tt++) {
            xws[(size_t)r * HID + tt * 16 + li] = f2bf(acc[tt][reg] * dv);
        }
    }
}

// ---------- GCN gather + bias/relu + logit dots ----------
__global__ __launch_bounds__(256) void k_gcn(const int* __restrict__ col,
                                             const int* __restrict__ row_ptr,
                                             const int* __restrict__ hist,
                                             const float* __restrict__ dinv,
                                             const unsigned short* __restrict__ xws,
                                             const float* __restrict__ b,
                                             const float* __restrict__ w_s,
                                             const float* __restrict__ w_d,
                                             float* __restrict__ h1f,
                                             unsigned short* __restrict__ h1b,
                                             unsigned short* __restrict__ X,
                                             float4* __restrict__ a_s,
                                             float4* __restrict__ a_d, int n) {
    int t = threadIdx.x, c = t & 63;
    int d = blockIdx.x * 4 + (t >> 6);
    if (d >= n) return;
    int start = row_ptr[d], cnt = hist[d];
    float acc = bf2f(xws[(size_t)d * HID + c]);       // self term
    int k = 0;
    for (; k + 3 < cnt; k += 4) {
        int s0 = col[start + k],     s1 = col[start + k + 1];
        int s2 = col[start + k + 2], s3 = col[start + k + 3];
        float v0 = bf2f(xws[(size_t)s0 * HID + c]);
        float v1 = bf2f(xws[(size_t)s1 * HID + c]);
        float v2 = bf2f(xws[(size_t)s2 * HID + c]);
        float v3 = bf2f(xws[(size_t)s3 * HID + c]);
        acc += (v0 + v1) + (v2 + v3);
    }
    for (; k < cnt; k++) acc += bf2f(xws[(size_t)col[start + k] * HID + c]);
    float h1c = fmaxf(acc * dinv[d] + b[c], 0.0f);
    h1f[(size_t)d * HID + c] = h1c;
    unsigned short hb = f2bf(h1c);
    h1b[(size_t)d * HID + c] = hb;
    X[(size_t)d * XK + 256 + c] = hb;
    float vs0 = h1c * w_s[c],       vs1 = h1c * w_s[64 + c];
    float vs2 = h1c * w_s[128 + c], vs3 = h1c * w_s[192 + c];
    float vd0 = h1c * w_d[c],       vd1 = h1c * w_d[64 + c];
    float vd2 = h1c * w_d[128 + c], vd3 = h1c * w_d[192 + c];
    for (int o = 32; o > 0; o >>= 1) {
        vs0 += __shfl_xor(vs0, o, 64); vs1 += __shfl_xor(vs1, o, 64);
        vs2 += __shfl_xor(vs2, o, 64); vs3 += __shfl_xor(vs3, o, 64);
        vd0 += __shfl_xor(vd0, o, 64); vd1 += __shfl_xor(vd1, o, 64);
        vd2 += __shfl_xor(vd2, o, 64); vd3 += __shfl_xor(vd3, o, 64);
    }
    if (c == 0) {
        a_s[d] = make_float4(vs0, vs1, vs2, vs3);
        a_d[d] = make_float4(vd0, vd1, vd2, vd3);
    }
}

// ---------- per-edge softmax weights (edge-parallel) ----------
__global__ void k_ew(const int* __restrict__ col, const int* __restrict__ col_d,
                     const float4* __restrict__ a_s, const float4* __restrict__ a_d,
                     float4* __restrict__ wbuf, int E) {
    int i = blockIdx.x * blockDim.x + threadIdx.x;
    if (i >= E) return;
    int s = col[i], d = col_d[i];
    float4 as = a_s[s], ad = a_d[d];
    float4 r;
    r.x = __expf(leaky(as.x + ad.x));
    r.y = __expf(leaky(as.y + ad.y));
    r.z = __expf(leaky(as.z + ad.z));
    r.w = __expf(leaky(as.w + ad.w));
    wbuf[i] = r;
}

// ---------- attention aggregation of h1 with precomputed weights ----------
__global__ __launch_bounds__(256) void k_attn(const int* __restrict__ col,
                                              const int* __restrict__ row_ptr,
                                              const int* __restrict__ hist,
                                              const float4* __restrict__ a_s,
                                              const float4* __restrict__ a_d,
                                              const float4* __restrict__ wbuf,
                                              const unsigned short* __restrict__ h1b,
                                              unsigned short* __restrict__ X, int n) {
    int t = threadIdx.x, c = t & 63;
    int d = blockIdx.x * 4 + (t >> 6);
    if (d >= n) return;
    float4 ad = a_d[d];
    float4 asd = a_s[d];
    float w0 = __expf(leaky(asd.x + ad.x));
    float w1 = __expf(leaky(asd.y + ad.y));
    float w2 = __expf(leaky(asd.z + ad.z));
    float w3 = __expf(leaky(asd.w + ad.w));
    float hs = bf2f(h1b[(size_t)d * HID + c]);
    float A0 = w0 * hs, A1 = w1 * hs, A2 = w2 * hs, A3 = w3 * hs;
    float l0 = w0, l1 = w1, l2 = w2, l3 = w3;
    int start = row_ptr[d], cnt = hist[d];
    int k = 0;
    for (; k + 3 < cnt; k += 4) {
        int s0 = col[start + k],     s1 = col[start + k + 1];
        int s2 = col[start + k + 2], s3 = col[start + k + 3];
        float4 e0 = wbuf[start + k],     e1 = wbuf[start + k + 1];
        float4 e2 = wbuf[start + k + 2], e3 = wbuf[start + k + 3];
        float hv0 = bf2f(h1b[(size_t)s0 * HID + c]);
        float hv1 = bf2f(h1b[(size_t)s1 * HID + c]);
        float hv2 = bf2f(h1b[(size_t)s2 * HID + c]);
        float hv3 = bf2f(h1b[(size_t)s3 * HID + c]);
        A0 += e0.x * hv0 + e1.x * hv1 + e2.x * hv2 + e3.x * hv3;
        A1 += e0.y * hv0 + e1.y * hv1 + e2.y * hv2 + e3.y * hv3;
        A2 += e0.z * hv0 + e1.z * hv1 + e2.z * hv2 + e3.z * hv3;
        A3 += e0.w * hv0 + e1.w * hv1 + e2.w * hv2 + e3.w * hv3;
        l0 += (e0.x + e1.x) + (e2.x + e3.x);
        l1 += (e0.y + e1.y) + (e2.y + e3.y);
        l2 += (e0.z + e1.z) + (e2.z + e3.z);
        l3 += (e0.w + e1.w) + (e2.w + e3.w);
    }
    for (; k < cnt; k++) {
        int s0 = col[start + k];
        float4 e0 = wbuf[start + k];
        float hv0 = bf2f(h1b[(size_t)s0 * HID + c]);
        A0 += e0.x * hv0; l0 += e0.x;
        A1 += e0.y * hv0; l1 += e0.y;
        A2 += e0.z * hv0; l2 += e0.z;
        A3 += e0.w * hv0; l3 += e0.w;
    }
    size_t base = (size_t)d * XK;
    X[base + c]       = f2bf(A0 / l0);
    X[base + 64 + c]  = f2bf(A1 / l1);
    X[base + 128 + c] = f2bf(A2 / l2);
    X[base + 192 + c] = f2bf(A3 / l3);
}

// ---------- post: MFMA GEMM X[n,320] @ pre-packed W -> agg|hp, + relu/residual/LN ----------
// 128 rows/block (2 row-tiles/wave); b-frags reused across row-tiles.
__global__ __launch_bounds__(256) void k_post(const unsigned short* __restrict__ Wt_g,
                                              const unsigned short* __restrict__ X,
                                              const float* __restrict__ h1f,
                                              const float* __restrict__ bp,
                                              const float* __restrict__ bg,
                                              const float* __restrict__ gamma,
                                              const float* __restrict__ beta,
                                              float* __restrict__ out, int n) {
    __shared__ unsigned short Wt[2560 * 8];   // 40 KB
    int t = threadIdx.x;
    for (int idx = t; idx < 2560; idx += 256)   // contiguous copy, conflict-free
        *(bf16x8*)(&Wt[idx * 8]) = *(const bf16x8*)(&Wt_g[(size_t)idx * 8]);
    __syncthreads();

    int lane = t & 63;
    int li = lane & 15, quad = lane >> 4;
    int w = t >> 6;
    int rbase = blockIdx.x * 128 + w * 32;       // 32 rows per wave (2 tiles)

    f32x4 acc_a[2][4], acc_h[2][4];
#pragma unroll
    for (int rt = 0; rt < 2; rt++)
#pragma unroll
        for (int i = 0; i < 4; i++) {
            acc_a[rt][i] = (f32x4){0.f, 0.f, 0.f, 0.f};
            acc_h[rt][i] = (f32x4){0.f, 0.f, 0.f, 0.f};
        }
#pragma unroll
    for (int ks = 0; ks < 10; ks++) {
        int kg = ks * 4 + quad;
        bf16x8 b0 = *(const bf16x8*)(&Wt[((kg * 64) + 0 * 16 + li) * 8]);
        bf16x8 b1 = *(const bf16x8*)(&Wt[((kg * 64) + 1 * 16 + li) * 8]);
        bf16x8 b2 = *(const bf16x8*)(&Wt[((kg * 64) + 2 * 16 + li) * 8]);
        bf16x8 b3 = *(const bf16x8*)(&Wt[((kg * 64) + 3 * 16 + li) * 8]);
#pragma unroll
        for (int rt = 0; rt < 2; rt++) {
            bf16x8 a = *(const bf16x8*)(X + (size_t)(rbase + rt * 16 + li) * XK
                                          + quad * 8 + ks * 32);
            if (ks < 8) {
                acc_a[rt][0] = __builtin_amdgcn_mfma_f32_16x16x32_bf16(a, b0, acc_a[rt][0], 0, 0, 0);
                acc_a[rt][1] = __builtin_amdgcn_mfma_f32_16x16x32_bf16(a, b1, acc_a[rt][1], 0, 0, 0);
                acc_a[rt][2] = __builtin_amdgcn_mfma_f32_16x16x32_bf16(a, b2, acc_a[rt][2], 0, 0, 0);
                acc_a[rt][3] = __builtin_amdgcn_mfma_f32_16x16x32_bf16(a, b3, acc_a[rt][3], 0, 0, 0);
            } else {
                acc_h[rt][0] = __builtin_amdgcn_mfma_f32_16x16x32_bf16(a, b0, acc_h[rt][0], 0, 0, 0);
                acc_h[rt][1] = __builtin_amdgcn_mfma_f32_16x16x32_bf16(a, b1, acc_h[rt][1], 0, 0, 0);
                acc_h[rt][2] = __builtin_amdgcn_mfma_f32_16x16x32_bf16(a, b2, acc_h[rt][2], 0, 0, 0);
                acc_h[rt][3] = __builtin_amdgcn_mfma_f32_16x16x32_bf16(a, b3, acc_h[rt][3], 0, 0, 0);
            }
        }
    }
    float bgv[4], bpv[4], gv[4], btv[4];
#pragma unroll
    for (int tt = 0; tt < 4; tt++) {
        int c = tt * 16 + li;
        bgv[tt] = bg[c]; bpv[tt] = bp[c]; gv[tt] = gamma[c]; btv[tt] = beta[c];
    }
#pragma unroll
    for (int rt = 0; rt < 2; rt++) {
#pragma unroll
        for (int reg = 0; reg < 4; reg++) {
            int r = rbase + rt * 16 + quad * 4 + reg;
            bool ok = (r < n);
            float hv[4];
            float s1 = 0.0f, s2 = 0.0f;
#pragma unroll
            for (int tt = 0; tt < 4; tt++) {
                int c = tt * 16 + li;
                float h1c = ok ? h1f[(size_t)r * HID + c] : 0.0f;
                float h2 = fmaxf(acc_a[rt][tt][reg] + bgv[tt], 0.0f);
                float h = h1c + h2 + acc_h[rt][tt][reg] + bpv[tt];
                hv[tt] = h;
                s1 += h; s2 += h * h;
            }
            for (int o = 8; o > 0; o >>= 1) {
                s1 += __shfl_xor(s1, o, 64);
                s2 += __shfl_xor(s2, o, 64);
            }
            float mu = s1 * (1.0f / 64.0f);
            float var = s2 * (1.0f / 64.0f) - mu * mu;
            float rs = rsqrtf(var + LN_EPS);
            if (ok) {
#pragma unroll
                for (int tt = 0; tt < 4; tt++) {
                    int c = tt * 16 + li;
                    out[(size_t)r * HID + c] = (hv[tt] - mu) * rs * gv[tt] + btv[tt];
                }
            }
        }
    }
}

extern "C" void kernel_launch(void* const* d_in, const int* in_sizes, int n_in,
                              void* d_out, int out_size, void* d_ws, size_t ws_size,
                              hipStream_t stream) {
    int n = in_sizes[0] / IN_DIM;
    int E = in_sizes[1] / 2;

    const float* x     = (const float*)d_in[0];
    const void*  ei    = d_in[1];
    const float* W_gcn = (const float*)d_in[2];
    const float* b_gcn = (const float*)d_in[3];
    const float* W_gat = (const float*)d_in[4];
    const float* att_s = (const float*)d_in[5];
    const float* att_d = (const float*)d_in[6];
    const float* b_gat = (const float*)d_in[7];
    const float* W_p   = (const float*)d_in[8];
    const float* b_p   = (const float*)d_in[9];
    const float* gamma = (const float*)d_in[10];
    const float* beta  = (const float*)d_in[11];

    int n_pad  = ((n + 255) / 256) * 256;
    int nscan  = n_pad / 256;                 // must be <= 256
    int n128   = ((n + 127) / 128) * 128;     // row padding for 128-row post tiles

    float* ws = (float*)d_ws;
    size_t off = 0;
    int*   flag    = (int*)(ws + off);  off += 4;
    int*   edges   = (int*)(ws + off);  off += (size_t)2 * E;
    int*   hist    = (int*)(ws + off);  off += n;
    int*   row_ptr = (int*)(ws + off);  off += n;
    int*   cursor  = (int*)(ws + off);  off += n;
    int*   tmp     = (int*)(ws + off);  off += n_pad;
    int*   partial = (int*)(ws + off);  off += 256;
    int*   colv    = (int*)(ws + off);  off += E;
    int*   col_d   = (int*)(ws + off);  off += E;
    float* dinv    = ws + off;          off += n;
    float* w_s     = ws + off;          off += HEADS * HID;
    float* w_d     = ws + off;          off += HEADS * HID;
    off = (off + 3) & ~(size_t)3;
    unsigned short* Wt_post = (unsigned short*)(ws + off); off += 2560 * 8 / 2;
    unsigned short* Wt_xw   = (unsigned short*)(ws + off); off += 1024 * 8 / 2;
    unsigned short* xws = (unsigned short*)(ws + off); off += (size_t)n * HID / 2;
    float* h1f     = ws + off;          off += (size_t)n * HID;
    off = (off + 3) & ~(size_t)3;
    unsigned short* h1b = (unsigned short*)(ws + off); off += (size_t)n * HID / 2;
    off = (off + 3) & ~(size_t)3;
    float4* a_sv   = (float4*)(ws + off); off += (size_t)n * 4;
    float4* a_dv   = (float4*)(ws + off); off += (size_t)n * 4;
    off = (off + 3) & ~(size_t)3;
    float4* wbuf   = (float4*)(ws + off); off += (size_t)E * 4;
    unsigned short* X = (unsigned short*)(ws + off); off += (size_t)n128 * XK / 2;

    const int* src = edges;
    const int* dst = edges + E;

    // detect dtype (block 0) + zero hist
    k_detect_zero<<<(n + 255) / 256, 256, 0, stream>>>(
        (const unsigned long long*)ei, E, n, flag, hist);
    // pre-pack weights for the two MFMA kernels
    k_wprep<<<14, 256, 0, stream>>>(W_gat, W_p, W_gcn, Wt_post, Wt_xw);
    // remap to int32 + dst histogram
    k_remap_hist<<<(2 * E + 255) / 256, 256, 0, stream>>>(ei, E, flag, edges, hist);

    // CSR scan + scatter (+ folded att prep)
    k_scan1<<<nscan, 256, 0, stream>>>(hist, tmp, partial, n);
    k_scan2_prep<<<1, 256, 0, stream>>>(partial, nscan, W_gat, att_s, att_d, w_s, w_d);
    k_scan3<<<nscan, 256, 0, stream>>>(tmp, partial, hist, row_ptr, cursor, dinv, n);
    k_scatter<<<(E + 255) / 256, 256, 0, stream>>>(src, dst, cursor, colv, col_d, E);

    // dense GCN projection via MFMA (bf16, pre-scaled by dinv)
    k_xw<<<(n + 63) / 64, 256, 0, stream>>>(x, Wt_xw, dinv, xws, n);

    // GCN gather + logit dots
    k_gcn<<<(n + 3) / 4, 256, 0, stream>>>(colv, row_ptr, hist, dinv, xws, b_gcn,
                                           w_s, w_d, h1f, h1b, X, a_sv, a_dv, n);

    // per-edge softmax weights (edge-parallel exp)
    k_ew<<<(E + 255) / 256, 256, 0, stream>>>(colv, col_d, a_sv, a_dv, wbuf, E);

    // attention aggregation of h1 -> X cols 0..255
    k_attn<<<(n + 3) / 4, 256, 0, stream>>>(colv, row_ptr, hist, a_sv, a_dv,
                                            wbuf, h1b, X, n);

    // MFMA post GEMM + relu/residual/LN
    k_post<<<(n + 127) / 128, 256, 0, stream>>>(Wt_post, X, h1f, b_p, b_gat,
                                                gamma, beta, (float*)d_out, n);
}